// Round 5
// baseline (6435.680 us; speedup 1.0000x reference)
//
#include <hip/hip_runtime.h>
#include <hip/hip_bf16.h>

typedef __bf16 bf16x8 __attribute__((ext_vector_type(8)));
typedef float  f32x4  __attribute__((ext_vector_type(4)));
typedef float  f32x2  __attribute__((ext_vector_type(2)));
typedef unsigned int u32x4 __attribute__((ext_vector_type(4)));
typedef unsigned short ushort_t;
static_assert(sizeof(bf16x8) == 16, "bf16x8 must be 16B");

#define DEV __device__ __forceinline__

DEV f32x4 mfma16(bf16x8 a, bf16x8 b, f32x4 c) {
    return __builtin_amdgcn_mfma_f32_16x16x32_bf16(a, b, c, 0, 0, 0);
}
DEV float wsum(float v) {
#pragma unroll
    for (int o = 32; o > 0; o >>= 1) v += __shfl_xor(v, o, 64);
    return v;
}
DEV float wmaxr(float v) {
#pragma unroll
    for (int o = 32; o > 0; o >>= 1) v = fmaxf(v, __shfl_xor(v, o, 64));
    return v;
}
DEV float sigm(float x)   { return 1.0f / (1.0f + __expf(-x)); }
DEV float tanh_f(float x) { return 2.0f / (1.0f + __expf(-2.0f * x)) - 1.0f; }

// async global->LDS, 16B per lane; lds dest must be wave-uniform base (+lane*16)
DEV void glds16(const __hip_bfloat16* g, __hip_bfloat16* l) {
    __builtin_amdgcn_global_load_lds(
        (const __attribute__((address_space(1))) unsigned int*)g,
        (__attribute__((address_space(3))) unsigned int*)l, 16, 0, 0);
}

DEV unsigned char f32_to_fp8(float v) {
    int p = __builtin_amdgcn_cvt_pk_fp8_f32(v, v, 0, false);
    return (unsigned char)(p & 0xFF);
}
DEV void fp8x4_to_f32(unsigned int w, float* out) {
    f32x2 lo = __builtin_amdgcn_cvt_pk_f32_fp8(w, false);
    f32x2 hi = __builtin_amdgcn_cvt_pk_f32_fp8(w, true);
    out[0] = lo[0]; out[1] = lo[1]; out[2] = hi[0]; out[3] = hi[1];
}

// ---------------- dtype detection: 1 = inputs are bf16, 0 = inputs are fp32 --
__global__ __launch_bounds__(128) void kdetect(const unsigned int* __restrict__ raw,
                                               int* __restrict__ mode) {
    __shared__ int cnt;
    if (threadIdx.x == 0) cnt = 0;
    __syncthreads();
    unsigned int w = raw[threadIdx.x];
    unsigned short lo = (unsigned short)(w & 0xFFFFu);
    unsigned int f32bits = ((unsigned int)lo) << 16;
    float v;
    __builtin_memcpy(&v, &f32bits, 4);
    float a = fabsf(v);
    if (a >= 1e-4f && a <= 1.0f) atomicAdd(&cnt, 1);
    __syncthreads();
    if (threadIdx.x == 0) *mode = (cnt >= 64) ? 1 : 0;
}

__global__ __launch_bounds__(256) void kcvt_bf16(const void* __restrict__ src,
                                                 __hip_bfloat16* __restrict__ dst,
                                                 int n, const int* __restrict__ mode) {
    int i = blockIdx.x * 256 + threadIdx.x;
    if (i >= n) return;
    if (*mode) dst[i] = ((const __hip_bfloat16*)src)[i];
    else       dst[i] = __float2bfloat16(((const float*)src)[i]);
}

__global__ __launch_bounds__(256) void kcvt_f32(const void* __restrict__ src,
                                                float* __restrict__ dst,
                                                int n, const int* __restrict__ mode) {
    int i = blockIdx.x * 256 + threadIdx.x;
    if (i >= n) return;
    if (*mode) dst[i] = __bfloat162float(((const __hip_bfloat16*)src)[i]);
    else       dst[i] = ((const float*)src)[i];
}

// --------- tiled transpose + convert: out_bf16[c][r] = (bf16)in[r][c] --------
__global__ __launch_bounds__(256) void ktranspose_cvt(const void* __restrict__ src,
                                                      __hip_bfloat16* __restrict__ out,
                                                      int R, int C,
                                                      const int* __restrict__ mode) {
    __shared__ float tile[64][65];
    int c0 = blockIdx.x * 64, r0 = blockIdx.y * 64;
    int tx = threadIdx.x & 63, ty = threadIdx.x >> 6;
    int m = *mode;
#pragma unroll
    for (int i = ty; i < 64; i += 4) {
        size_t ix = (size_t)(r0 + i) * C + (c0 + tx);
        tile[i][tx] = m ? __bfloat162float(((const __hip_bfloat16*)src)[ix])
                        : ((const float*)src)[ix];
    }
    __syncthreads();
#pragma unroll
    for (int i = ty; i < 64; i += 4)
        out[(size_t)(c0 + i) * R + (r0 + tx)] = __float2bfloat16(tile[tx][i]);
}

// ------ prep: G tables, gate-interleaved: G[dh][v][u<512][g<4] = E@Wi (+b) ---
__global__ __launch_bounds__(256) void kprep_gtab(
    const __hip_bfloat16* __restrict__ E,    // [128][128]
    const __hip_bfloat16* __restrict__ WiT,  // [2][2048][256]
    const float* __restrict__ bF,
    const float* __restrict__ bB,
    float* __restrict__ G)                   // [4][128][512][4]
{
    int dh = blockIdx.x >> 6;
    int dir = dh >> 1, half = dh & 1;
    int m0 = ((blockIdx.x >> 5) & 1) * 64;
    int n0 = (blockIdx.x & 31) * 64;
    int lane = threadIdx.x & 63, wid = threadIdx.x >> 6;
    int wrow = wid >> 1, wcol = wid & 1;
    int r16 = lane & 15, quad = lane >> 4;

    f32x4 acc[2][2] = {};
    const __hip_bfloat16* Ap = E + (size_t)(m0 + wrow * 32 + r16) * 128 + quad * 8;
    const __hip_bfloat16* Bp = WiT + (size_t)dir * 2048 * 256
                             + (size_t)(n0 + wcol * 32 + r16) * 256 + half * 128 + quad * 8;
#pragma unroll
    for (int kb = 0; kb < 128; kb += 32) {
        bf16x8 a0 = *(const bf16x8*)(Ap + kb);
        bf16x8 a1 = *(const bf16x8*)(Ap + 16 * 128 + kb);
        bf16x8 b0 = *(const bf16x8*)(Bp + kb);
        bf16x8 b1 = *(const bf16x8*)(Bp + 16 * 256 + kb);
        acc[0][0] = mfma16(a0, b0, acc[0][0]);
        acc[0][1] = mfma16(a0, b1, acc[0][1]);
        acc[1][0] = mfma16(a1, b0, acc[1][0]);
        acc[1][1] = mfma16(a1, b1, acc[1][1]);
    }
    const float* bias = dir ? bB : bF;
    float* Gt = G + (size_t)dh * 128 * 2048;
#pragma unroll
    for (int rt = 0; rt < 2; rt++)
#pragma unroll
        for (int ct = 0; ct < 2; ct++)
#pragma unroll
            for (int r = 0; r < 4; r++) {
                int mm = m0 + wrow * 32 + rt * 16 + quad * 4 + r;
                int j = n0 + wcol * 32 + ct * 16 + r16;
                float v = acc[rt][ct][r];
                if (half == 0) v += bias[j];
                int g = j >> 9, u = j & 511;
                Gt[((size_t)mm * 512 + u) * 4 + g] = v;
            }
}

// ---------------- prep: VX[t][j] = field_emb @ v_Wi + v_b --------------------
__global__ __launch_bounds__(256) void kprep_vx(
    const __hip_bfloat16* __restrict__ fe,    // [32][1024]
    const __hip_bfloat16* __restrict__ vWiT,  // [4096][1024]
    const float* __restrict__ vb,             // [4096]
    float* __restrict__ VX)                   // [32][4096]
{
    int n0 = blockIdx.x * 128;
    int lane = threadIdx.x & 63, wid = threadIdx.x >> 6;
    int r16 = lane & 15, quad = lane >> 4;
    f32x4 acc[2][2] = {};
    const __hip_bfloat16* Ap = fe + (size_t)r16 * 1024 + quad * 8;
    const __hip_bfloat16* Bp = vWiT + (size_t)(n0 + wid * 32 + r16) * 1024 + quad * 8;
    for (int kb = 0; kb < 1024; kb += 32) {
        bf16x8 a0 = *(const bf16x8*)(Ap + kb);
        bf16x8 a1 = *(const bf16x8*)(Ap + 16 * 1024 + kb);
        bf16x8 b0 = *(const bf16x8*)(Bp + kb);
        bf16x8 b1 = *(const bf16x8*)(Bp + 16 * 1024 + kb);
        acc[0][0] = mfma16(a0, b0, acc[0][0]);
        acc[0][1] = mfma16(a0, b1, acc[0][1]);
        acc[1][0] = mfma16(a1, b0, acc[1][0]);
        acc[1][1] = mfma16(a1, b1, acc[1][1]);
    }
#pragma unroll
    for (int rt = 0; rt < 2; rt++)
#pragma unroll
        for (int ct = 0; ct < 2; ct++)
#pragma unroll
            for (int r = 0; r < 4; r++) {
                int m = rt * 16 + quad * 4 + r;
                int j = n0 + wid * 32 + ct * 16 + r16;
                VX[(size_t)m * 4096 + j] = acc[rt][ct][r] + vb[j];
            }
}

// ======== encoder LSTM step: 512 blocks (dir x 32 mt x 8 us), 32m x 64u ======
__global__ __launch_bounds__(256, 2) void kenc_step(
    int t,
    const __hip_bfloat16* __restrict__ WhT,   // [2][2048][512]
    const float* __restrict__ Gtab,           // [4][128][512][4]
    const int* __restrict__ exs,
    const int* __restrict__ cls,
    const __hip_bfloat16* __restrict__ h_in,  // [2][1024][512]
    __hip_bfloat16* __restrict__ h_out,
    float* __restrict__ c_st,                 // [2][1024][512]
    unsigned char* __restrict__ ctx8)         // [64][256][4][1024] fp8 (x16)
{
    __shared__ __align__(16) __hip_bfloat16 sA[2][32 * 64];
    __shared__ __align__(16) __hip_bfloat16 sB[2][256 * 64];

    int bid = blockIdx.x;
    int dir = bid >> 8;
    int mt  = (bid >> 3) & 31;
    int us  = bid & 7;
    int l = dir ? (63 - t) : t;
    int m0 = mt * 32, u0 = us * 64;

    int lane = threadIdx.x & 63, w = threadIdx.x >> 6;
    int r16 = lane & 15, quad = lane >> 4;
    int srow = lane >> 3, scol = (lane & 7) * 8;   // 8 rows per glds16 call

    const __hip_bfloat16* Ab = h_in + (size_t)dir * 1024 * 512;
    const __hip_bfloat16* Bb = WhT + (size_t)dir * 2048 * 512;

    f32x4 acc[4][2] = {};  // [gate][mi]

    auto stage = [&](int buf, int it) {
        int kb = it * 64;
        // A: 32 rows x 64 k; wave w stages rows [w*8, w*8+8)
        glds16(Ab + (size_t)(m0 + w * 8 + srow) * 512 + kb + scol,
               &sA[buf][(w * 8) * 64]);
        // B: 256 rows (4 gates x 64 u) x 64 k; wave w rows [w*64, w*64+64)
#pragma unroll
        for (int c = 0; c < 8; c++) {
            int rl = w * 64 + c * 8;
            int rr = rl + srow;
            int g = rr >> 6, j = rr & 63;
            glds16(Bb + (size_t)(g * 512 + u0 + j) * 512 + kb + scol,
                   &sB[buf][rl * 64]);
        }
    };

    stage(0, 0);
    __syncthreads();
    int buf = 0;
    const int NIT = 8;  // 512/64
    for (int it = 0; it < NIT; it++) {
        if (it + 1 < NIT) stage(buf ^ 1, it + 1);
#pragma unroll
        for (int k32 = 0; k32 < 64; k32 += 32) {
            bf16x8 a[2], bf[4];
#pragma unroll
            for (int mi = 0; mi < 2; mi++)
                a[mi] = *(const bf16x8*)&sA[buf][(mi * 16 + r16) * 64 + k32 + quad * 8];
#pragma unroll
            for (int g = 0; g < 4; g++)
                bf[g] = *(const bf16x8*)&sB[buf][(g * 64 + w * 16 + r16) * 64 + k32 + quad * 8];
#pragma unroll
            for (int g = 0; g < 4; g++)
#pragma unroll
                for (int mi = 0; mi < 2; mi++)
                    acc[g][mi] = mfma16(a[mi], bf[g], acc[g][mi]);
        }
        __syncthreads();
        buf ^= 1;
    }

    // epilogue: thread owns u = u0 + w*16 + r16, 8 m's
    int u = u0 + w * 16 + r16;
    size_t cbase = (size_t)dir * 1024 * 512;
    const float* GeT = Gtab + (size_t)(dir * 2) * 128 * 2048;
    const float* GcT = GeT + 128 * 2048;
#pragma unroll
    for (int mi = 0; mi < 2; mi++)
#pragma unroll
        for (int r = 0; r < 4; r++) {
            int m = m0 + mi * 16 + quad * 4 + r;
            int vE = exs[l * 1024 + m], vC = cls[l * 1024 + m];
            f32x4 ge = *(const f32x4*)&GeT[((size_t)vE * 512 + u) * 4];
            f32x4 gc = *(const f32x4*)&GcT[((size_t)vC * 512 + u) * 4];
            float gi = acc[0][mi][r] + ge[0] + gc[0];
            float gf = acc[1][mi][r] + ge[1] + gc[1];
            float gg = acc[2][mi][r] + ge[2] + gc[2];
            float go = acc[3][mi][r] + ge[3] + gc[3];
            size_t cix = cbase + (size_t)m * 512 + u;
            float cn = sigm(gf) * c_st[cix] + sigm(gi) * tanh_f(gg);
            c_st[cix] = cn;
            float hn = sigm(go) * tanh_f(cn);
            h_out[cix] = __float2bfloat16(hn);
            ctx8[(((size_t)l * 256 + (m >> 2)) * 4 + (m & 3)) * 1024 + dir * 512 + u]
                = f32_to_fp8(hn * 16.0f);
        }
}

// ======== decoder fused GEMM: cell (0..127: 32m x 64u) + q (128..255) ========
__global__ __launch_bounds__(256, 2) void kdec_gemm(
    int t,
    const __hip_bfloat16* __restrict__ vWhT,   // [4096][1024]
    const __hip_bfloat16* __restrict__ WattnT, // [1024][1024]
    const float* __restrict__ VX,              // [32][4096]
    const __hip_bfloat16* __restrict__ h_in,   // [256][1024]  (h_t)
    __hip_bfloat16* __restrict__ h_out,        // [256][1024]  (h_{t+1})
    float* __restrict__ c_st,                  // [256][1024]
    float* __restrict__ qout)                  // [256][1024]  (q_t)
{
    __shared__ __align__(16) __hip_bfloat16 sA[2][32 * 64];
    __shared__ __align__(16) __hip_bfloat16 sB[2][256 * 64];

    int bid = blockIdx.x;
    int lane = threadIdx.x & 63, w = threadIdx.x >> 6;
    int r16 = lane & 15, quad = lane >> 4;
    int srow = lane >> 3, scol = (lane & 7) * 8;
    const int NIT = 16;  // 1024/64

    if (bid < 128) {
        // ---- cell path: 32m x (4 gates x 64u)
        int m0 = (bid >> 4) * 32, u0 = (bid & 15) * 64;
        f32x4 acc[4][2] = {};
        auto stage = [&](int buf, int it) {
            int kb = it * 64;
            glds16(h_in + (size_t)(m0 + w * 8 + srow) * 1024 + kb + scol,
                   &sA[buf][(w * 8) * 64]);
#pragma unroll
            for (int c = 0; c < 8; c++) {
                int rl = w * 64 + c * 8;
                int rr = rl + srow;
                int g = rr >> 6, j = rr & 63;
                glds16(vWhT + (size_t)(g * 1024 + u0 + j) * 1024 + kb + scol,
                       &sB[buf][rl * 64]);
            }
        };
        stage(0, 0);
        __syncthreads();
        int buf = 0;
        for (int it = 0; it < NIT; it++) {
            if (it + 1 < NIT) stage(buf ^ 1, it + 1);
#pragma unroll
            for (int k32 = 0; k32 < 64; k32 += 32) {
                bf16x8 a[2], bf[4];
#pragma unroll
                for (int mi = 0; mi < 2; mi++)
                    a[mi] = *(const bf16x8*)&sA[buf][(mi * 16 + r16) * 64 + k32 + quad * 8];
#pragma unroll
                for (int g = 0; g < 4; g++)
                    bf[g] = *(const bf16x8*)&sB[buf][(g * 64 + w * 16 + r16) * 64 + k32 + quad * 8];
#pragma unroll
                for (int g = 0; g < 4; g++)
#pragma unroll
                    for (int mi = 0; mi < 2; mi++)
                        acc[g][mi] = mfma16(a[mi], bf[g], acc[g][mi]);
            }
            __syncthreads();
            buf ^= 1;
        }
        int u = u0 + w * 16 + r16;
        const float* vx = VX + (size_t)t * 4096;
        float v0 = vx[u], v1 = vx[1024 + u], v2 = vx[2048 + u], v3 = vx[3072 + u];
#pragma unroll
        for (int mi = 0; mi < 2; mi++)
#pragma unroll
            for (int r = 0; r < 4; r++) {
                int m = m0 + mi * 16 + quad * 4 + r;
                float gi = acc[0][mi][r] + v0;
                float gf = acc[1][mi][r] + v1;
                float gg = acc[2][mi][r] + v2;
                float go = acc[3][mi][r] + v3;
                size_t cix = (size_t)m * 1024 + u;
                float cn = sigm(gf) * c_st[cix] + sigm(gi) * tanh_f(gg);
                c_st[cix] = cn;
                h_out[cix] = __float2bfloat16(sigm(go) * tanh_f(cn));
            }
    } else {
        // ---- q path: 32m x 64n GEMM vs WattnT, fp32 out
        int b2 = bid - 128;
        int m0 = (b2 >> 4) * 32, n0 = (b2 & 15) * 64;
        f32x4 acc[2] = {};
        auto stage = [&](int buf, int it) {
            int kb = it * 64;
            glds16(h_in + (size_t)(m0 + w * 8 + srow) * 1024 + kb + scol,
                   &sA[buf][(w * 8) * 64]);
#pragma unroll
            for (int c = 0; c < 2; c++) {
                int rl = w * 16 + c * 8;
                glds16(WattnT + (size_t)(n0 + rl + srow) * 1024 + kb + scol,
                       &sB[buf][rl * 64]);
            }
        };
        stage(0, 0);
        __syncthreads();
        int buf = 0;
        for (int it = 0; it < NIT; it++) {
            if (it + 1 < NIT) stage(buf ^ 1, it + 1);
#pragma unroll
            for (int k32 = 0; k32 < 64; k32 += 32) {
                bf16x8 a[2];
#pragma unroll
                for (int mi = 0; mi < 2; mi++)
                    a[mi] = *(const bf16x8*)&sA[buf][(mi * 16 + r16) * 64 + k32 + quad * 8];
                bf16x8 bf = *(const bf16x8*)&sB[buf][(w * 16 + r16) * 64 + k32 + quad * 8];
#pragma unroll
                for (int mi = 0; mi < 2; mi++)
                    acc[mi] = mfma16(a[mi], bf, acc[mi]);
            }
            __syncthreads();
            buf ^= 1;
        }
        int n = n0 + w * 16 + r16;
#pragma unroll
        for (int mi = 0; mi < 2; mi++)
#pragma unroll
            for (int r = 0; r < 4; r++) {
                int m = m0 + mi * 16 + quad * 4 + r;
                qout[(size_t)m * 1024 + n] = acc[mi][r];
            }
    }
}

// ======== attention (fp8 ctx, 2x8 register-chunked) + pool + logits + NLL ====
__global__ __launch_bounds__(1024, 1) void kattn(
    int t,
    const float* __restrict__ q,              // [256][1024]
    const unsigned char* __restrict__ ctx8,   // [64][256][4][1024] fp8 (x16)
    const __hip_bfloat16* __restrict__ hcur,  // [256][1024]
    const __hip_bfloat16* __restrict__ WcT,   // [64][2048]
    const float* __restrict__ bcomp,          // [64]
    const int* __restrict__ actions,          // [256][32]
    float* __restrict__ nll)                  // [256]
{
    __shared__ float scacc[16][64 * 17];      // stride-17: conflict-free
    __shared__ float sM[4][4], sS[4][4];
    __shared__ float spool[1024];
    __shared__ float shb[1024];
    __shared__ float slg[64];

    int b = blockIdx.x;
    int tid = threadIdx.x;
    int lane = tid & 63, wid = tid >> 6;
    int n = wid & 3, lq = wid >> 2;           // wave: io-example n, l-chunk lq

    float qr[16];
    {
        const float* qp = q + (size_t)b * 1024 + lane * 16;
#pragma unroll
        for (int i = 0; i < 16; i++) qr[i] = qp[i] * 0.0625f;  // fold 1/16 scale
    }

    const size_t LSTR = 1024 * 1024;          // ctx8 l-stride bytes
    const unsigned char* cb = ctx8 + ((size_t)b * 4 + n) * 1024 + lane * 16;

    float mx = -1e30f, ssum = 0.f;
    float cacc[16];
#pragma unroll
    for (int i = 0; i < 16; i++) cacc[i] = 0.f;

#pragma unroll
    for (int ch = 0; ch < 2; ch++) {
        u32x4 rw[8];
#pragma unroll
        for (int j = 0; j < 8; j++) {
            int l = lq * 16 + ch * 8 + j;
            rw[j] = __builtin_nontemporal_load((const u32x4*)(cb + (size_t)l * LSTR));
        }
        float s[8];
#pragma unroll
        for (int j = 0; j < 8; j++) {
            float rv[16];
            fp8x4_to_f32(rw[j][0], rv);
            fp8x4_to_f32(rw[j][1], rv + 4);
            fp8x4_to_f32(rw[j][2], rv + 8);
            fp8x4_to_f32(rw[j][3], rv + 12);
            float d = 0.f;
#pragma unroll
            for (int i = 0; i < 16; i++) d += rv[i] * qr[i];
            s[j] = wsum(d);
        }
        float mc = s[0];
#pragma unroll
        for (int j = 1; j < 8; j++) mc = fmaxf(mc, s[j]);
        float mn = fmaxf(mx, mc);
        float sc = __expf(mx - mn);
        ssum *= sc;
#pragma unroll
        for (int i = 0; i < 16; i++) cacc[i] *= sc;
#pragma unroll
        for (int j = 0; j < 8; j++) {
            float p = __expf(s[j] - mn);
            ssum += p;
            float rv[16];
            fp8x4_to_f32(rw[j][0], rv);
            fp8x4_to_f32(rw[j][1], rv + 4);
            fp8x4_to_f32(rw[j][2], rv + 8);
            fp8x4_to_f32(rw[j][3], rv + 12);
#pragma unroll
            for (int i = 0; i < 16; i++) cacc[i] += p * rv[i];
        }
        mx = mn;
    }

#pragma unroll
    for (int i = 0; i < 16; i++) scacc[wid][lane * 17 + i] = cacc[i];
    if (lane == 0) { sM[n][lq] = mx; sS[n][lq] = ssum; }
    shb[tid] = __bfloat162float(hcur[(size_t)b * 1024 + tid]);
    __syncthreads();

    // merge 4 l-chunks per n, normalize (incl. 1/16 fp8 scale), max-pool over n
    {
        int eo = (tid >> 4) * 17 + (tid & 15);
        float pool = -1e30f;
#pragma unroll
        for (int nn = 0; nn < 4; nn++) {
            float M = fmaxf(fmaxf(sM[nn][0], sM[nn][1]), fmaxf(sM[nn][2], sM[nn][3]));
            float S = 0.f, V = 0.f;
#pragma unroll
            for (int kq = 0; kq < 4; kq++) {
                float sc = __expf(sM[nn][kq] - M);
                S += sS[nn][kq] * sc;
                V += scacc[nn * 4 + kq][eo] * sc;
            }
            pool = fmaxf(pool, V / (16.0f * S));
        }
        spool[tid] = pool;
    }
    __syncthreads();

    // logits: wave wid computes prods wid*4 .. wid*4+3
#pragma unroll
    for (int pi = 0; pi < 4; pi++) {
        int p = wid * 4 + pi;
        const __hip_bfloat16* wr = WcT + (size_t)p * 2048;
        float s = 0.f;
#pragma unroll
        for (int jj = 0; jj < 16; jj++) {
            int e = lane + jj * 64;
            s += shb[e] * __bfloat162float(wr[e]);
            s += spool[e] * __bfloat162float(wr[1024 + e]);
        }
        s = wsum(s);
        if (lane == 0) slg[p] = s + bcomp[p];
    }
    __syncthreads();
    if (tid < 64) {
        float v = slg[tid];
        float m2 = wmaxr(v);
        float se = wsum(__expf(v - m2));
        int a = actions[b * 32 + t];
        if (tid == a) nll[b] -= (v - m2 - __logf(se));
    }
}

// ---------------- decoder init: max-pool final states over io examples -------
__global__ __launch_bounds__(256) void kinit_dec(
    const __hip_bfloat16* __restrict__ hf,  // final h (buf0): [2][1024][512]
    const float* __restrict__ cf,
    __hip_bfloat16* __restrict__ h0,        // [256][1024]
    float* __restrict__ c0)
{
    int idx = blockIdx.x * 256 + threadIdx.x;
    int b = idx >> 10, e = idx & 1023;
    int dir = e >> 9, u = e & 511;
    const __hip_bfloat16* hs = hf + (size_t)dir * 1024 * 512;
    const float* cs = cf + (size_t)dir * 1024 * 512;
    float hv = -3.4e38f, cv = -3.4e38f;
#pragma unroll
    for (int n = 0; n < 4; n++) {
        size_t ix = (size_t)(b * 4 + n) * 512 + u;
        hv = fmaxf(hv, __bfloat162float(hs[ix]));
        cv = fmaxf(cv, cs[ix]);
    }
    h0[idx] = __float2bfloat16(hv);
    c0[idx] = cv;
}

__global__ void kfinal(const float* __restrict__ nll, void* __restrict__ out,
                       const int* __restrict__ mode) {
    int i = threadIdx.x;
    if (*mode) ((__hip_bfloat16*)out)[i] = __float2bfloat16(nll[i]);
    else       ((float*)out)[i] = nll[i];
}

// -----------------------------------------------------------------------------
extern "C" void kernel_launch(void* const* d_in, const int* in_sizes, int n_in,
                              void* d_out, int out_size, void* d_ws, size_t ws_size,
                              hipStream_t stream) {
    const int* exs = (const int*)d_in[0];
    const int* cls = (const int*)d_in[1];
    const void* E_raw     = d_in[2];
    const void* WiF_raw   = d_in[3];
    const void* WhF_raw   = d_in[4];
    const void* bF_raw    = d_in[5];
    const void* WiB_raw   = d_in[6];
    const void* WhB_raw   = d_in[7];
    const void* bB_raw    = d_in[8];
    const void* Wattn_raw = d_in[9];
    const void* Wcomp_raw = d_in[10];
    const void* bcomp_raw = d_in[11];
    const void* vWi_raw   = d_in[12];
    const void* vWh_raw   = d_in[13];
    const void* vb_raw    = d_in[14];
    const void* fe_raw    = d_in[15];
    const int* actions = (const int*)d_in[16];
    (void)in_sizes; (void)n_in; (void)out_size; (void)ws_size;

    char* w = (char*)d_ws;
    size_t off = 0;
    auto take = [&](size_t bytes) -> char* {
        char* p = w + off;
        off = (off + bytes + 255) & ~(size_t)255;
        return p;
    };
    __hip_bfloat16* WhT    = (__hip_bfloat16*)take(2ull * 2048 * 512 * 2);
    __hip_bfloat16* WiT    = (__hip_bfloat16*)take(2ull * 2048 * 256 * 2);
    __hip_bfloat16* vWhT   = (__hip_bfloat16*)take(4096ull * 1024 * 2);
    __hip_bfloat16* vWiT   = (__hip_bfloat16*)take(4096ull * 1024 * 2);
    __hip_bfloat16* WattnT = (__hip_bfloat16*)take(1024ull * 1024 * 2);
    __hip_bfloat16* WcT    = (__hip_bfloat16*)take(64ull * 2048 * 2);
    __hip_bfloat16* Ebf    = (__hip_bfloat16*)take(128ull * 128 * 2);
    __hip_bfloat16* febf   = (__hip_bfloat16*)take(32ull * 1024 * 2);
    float* bFf   = (float*)take(2048 * 4);
    float* bBf   = (float*)take(2048 * 4);
    float* bcf   = (float*)take(64 * 4);
    float* vbf   = (float*)take(4096 * 4);
    float* Gtab  = (float*)take(4ull * 128 * 2048 * 4);
    float* VX    = (float*)take(32ull * 4096 * 4);
    __hip_bfloat16* hEnc = (__hip_bfloat16*)take(2ull * 2 * 1024 * 512 * 2); // [buf][dir][1024][512]
    float* cEnc = (float*)take(2ull * 1024 * 512 * 4);
    __hip_bfloat16* hDec = (__hip_bfloat16*)take(2ull * 256 * 1024 * 2);
    float* cDec = (float*)take(256ull * 1024 * 4);
    float* qbuf = (float*)take(256ull * 1024 * 4);
    float* nll  = (float*)take(256 * 4);
    int*   mode = (int*)take(256);
    unsigned char* ctx8 = (unsigned char*)take(64ull * 1024 * 1024);  // fp8 [64][256][4][1024]

    (void)hipMemsetAsync(hEnc, 0, 2ull * 1024 * 512 * 2, stream);  // h buf0, both dirs
    (void)hipMemsetAsync(cEnc, 0, 2ull * 1024 * 512 * 4, stream);
    (void)hipMemsetAsync(nll, 0, 256 * 4, stream);

    kdetect<<<1, 128, 0, stream>>>((const unsigned int*)E_raw, mode);

    kcvt_bf16<<<64, 256, 0, stream>>>(E_raw,  Ebf,  128 * 128, mode);
    kcvt_bf16<<<128, 256, 0, stream>>>(fe_raw, febf, 32 * 1024, mode);
    kcvt_f32<<<8, 256, 0, stream>>>(bF_raw, bFf, 2048, mode);
    kcvt_f32<<<8, 256, 0, stream>>>(bB_raw, bBf, 2048, mode);
    kcvt_f32<<<1, 256, 0, stream>>>(bcomp_raw, bcf, 64, mode);
    kcvt_f32<<<16, 256, 0, stream>>>(vb_raw, vbf, 4096, mode);

    ktranspose_cvt<<<dim3(32, 8),  256, 0, stream>>>(WhF_raw,   WhT,              512, 2048, mode);
    ktranspose_cvt<<<dim3(32, 8),  256, 0, stream>>>(WhB_raw,   WhT + 2048 * 512, 512, 2048, mode);
    ktranspose_cvt<<<dim3(32, 4),  256, 0, stream>>>(WiF_raw,   WiT,              256, 2048, mode);
    ktranspose_cvt<<<dim3(32, 4),  256, 0, stream>>>(WiB_raw,   WiT + 2048 * 256, 256, 2048, mode);
    ktranspose_cvt<<<dim3(64, 16), 256, 0, stream>>>(vWh_raw,   vWhT,            1024, 4096, mode);
    ktranspose_cvt<<<dim3(64, 16), 256, 0, stream>>>(vWi_raw,   vWiT,            1024, 4096, mode);
    ktranspose_cvt<<<dim3(16, 16), 256, 0, stream>>>(Wattn_raw, WattnT,          1024, 1024, mode);
    ktranspose_cvt<<<dim3(1, 32),  256, 0, stream>>>(Wcomp_raw, WcT,             2048, 64,   mode);

    kprep_gtab<<<256, 256, 0, stream>>>(Ebf, WiT, bFf, bBf, Gtab);
    kprep_vx<<<32, 256, 0, stream>>>(febf, vWiT, vbf, VX);

    const size_t HB = 2ull * 1024 * 512;
    for (int t = 0; t < 64; t++) {
        kenc_step<<<512, 256, 0, stream>>>(t, WhT, Gtab, exs, cls,
                                           hEnc + (size_t)(t & 1) * HB,
                                           hEnc + (size_t)((t + 1) & 1) * HB,
                                           cEnc, ctx8);
    }
    kinit_dec<<<1024, 256, 0, stream>>>(hEnc, cEnc, hDec, cDec);

    const size_t HD = 256ull * 1024;
    for (int t = 0; t < 32; t++) {
        const __hip_bfloat16* hcur = hDec + (size_t)(t & 1) * HD;
        kdec_gemm<<<256, 256, 0, stream>>>(t, vWhT, WattnT, VX, hcur,
                                           hDec + (size_t)((t + 1) & 1) * HD, cDec, qbuf);
        kattn<<<256, 1024, 0, stream>>>(t, qbuf, ctx8, hcur, WcT, bcf, actions, nll);
    }
    kfinal<<<1, 256, 0, stream>>>(nll, d_out, mode);
}

// Round 6
// 5349.841 us; speedup vs baseline: 1.2030x; 1.2030x over previous
//
#include <hip/hip_runtime.h>
#include <hip/hip_bf16.h>

typedef __bf16 bf16x8 __attribute__((ext_vector_type(8)));
typedef float  f32x4  __attribute__((ext_vector_type(4)));
typedef float  f32x2  __attribute__((ext_vector_type(2)));
typedef unsigned int u32x4 __attribute__((ext_vector_type(4)));
typedef unsigned short ushort_t;
static_assert(sizeof(bf16x8) == 16, "bf16x8 must be 16B");

#define DEV __device__ __forceinline__

DEV f32x4 mfma16(bf16x8 a, bf16x8 b, f32x4 c) {
    return __builtin_amdgcn_mfma_f32_16x16x32_bf16(a, b, c, 0, 0, 0);
}
DEV float wsum(float v) {
#pragma unroll
    for (int o = 32; o > 0; o >>= 1) v += __shfl_xor(v, o, 64);
    return v;
}
DEV float wmaxr(float v) {
#pragma unroll
    for (int o = 32; o > 0; o >>= 1) v = fmaxf(v, __shfl_xor(v, o, 64));
    return v;
}
DEV float sigm(float x)   { return 1.0f / (1.0f + __expf(-x)); }
DEV float tanh_f(float x) { return 2.0f / (1.0f + __expf(-2.0f * x)) - 1.0f; }

// async global->LDS, 16B per lane; lds dest must be wave-uniform base (+lane*16)
DEV void glds16(const __hip_bfloat16* g, __hip_bfloat16* l) {
    __builtin_amdgcn_global_load_lds(
        (const __attribute__((address_space(1))) unsigned int*)g,
        (__attribute__((address_space(3))) unsigned int*)l, 16, 0, 0);
}

DEV unsigned char f32_to_fp8(float v) {
    int p = __builtin_amdgcn_cvt_pk_fp8_f32(v, v, 0, false);
    return (unsigned char)(p & 0xFF);
}
DEV void fp8x4_to_f32(unsigned int w, float* out) {
    f32x2 lo = __builtin_amdgcn_cvt_pk_f32_fp8(w, false);
    f32x2 hi = __builtin_amdgcn_cvt_pk_f32_fp8(w, true);
    out[0] = lo[0]; out[1] = lo[1]; out[2] = hi[0]; out[3] = hi[1];
}

// ---------------- dtype detection: 1 = inputs are bf16, 0 = inputs are fp32 --
__global__ __launch_bounds__(128) void kdetect(const unsigned int* __restrict__ raw,
                                               int* __restrict__ mode) {
    __shared__ int cnt;
    if (threadIdx.x == 0) cnt = 0;
    __syncthreads();
    unsigned int w = raw[threadIdx.x];
    unsigned short lo = (unsigned short)(w & 0xFFFFu);
    unsigned int f32bits = ((unsigned int)lo) << 16;
    float v;
    __builtin_memcpy(&v, &f32bits, 4);
    float a = fabsf(v);
    if (a >= 1e-4f && a <= 1.0f) atomicAdd(&cnt, 1);
    __syncthreads();
    if (threadIdx.x == 0) *mode = (cnt >= 64) ? 1 : 0;
}

__global__ __launch_bounds__(256) void kcvt_bf16(const void* __restrict__ src,
                                                 __hip_bfloat16* __restrict__ dst,
                                                 int n, const int* __restrict__ mode) {
    int i = blockIdx.x * 256 + threadIdx.x;
    if (i >= n) return;
    if (*mode) dst[i] = ((const __hip_bfloat16*)src)[i];
    else       dst[i] = __float2bfloat16(((const float*)src)[i]);
}

__global__ __launch_bounds__(256) void kcvt_f32(const void* __restrict__ src,
                                                float* __restrict__ dst,
                                                int n, const int* __restrict__ mode) {
    int i = blockIdx.x * 256 + threadIdx.x;
    if (i >= n) return;
    if (*mode) dst[i] = __bfloat162float(((const __hip_bfloat16*)src)[i]);
    else       dst[i] = ((const float*)src)[i];
}

// --------- tiled transpose + convert: out_bf16[c][r] = (bf16)in[r][c] --------
__global__ __launch_bounds__(256) void ktranspose_cvt(const void* __restrict__ src,
                                                      __hip_bfloat16* __restrict__ out,
                                                      int R, int C,
                                                      const int* __restrict__ mode) {
    __shared__ float tile[64][65];
    int c0 = blockIdx.x * 64, r0 = blockIdx.y * 64;
    int tx = threadIdx.x & 63, ty = threadIdx.x >> 6;
    int m = *mode;
#pragma unroll
    for (int i = ty; i < 64; i += 4) {
        size_t ix = (size_t)(r0 + i) * C + (c0 + tx);
        tile[i][tx] = m ? __bfloat162float(((const __hip_bfloat16*)src)[ix])
                        : ((const float*)src)[ix];
    }
    __syncthreads();
#pragma unroll
    for (int i = ty; i < 64; i += 4)
        out[(size_t)(c0 + i) * R + (r0 + tx)] = __float2bfloat16(tile[tx][i]);
}

// ------ prep: G tables, gate-interleaved: G[dh][v][u<512][g<4] = E@Wi (+b) ---
__global__ __launch_bounds__(256) void kprep_gtab(
    const __hip_bfloat16* __restrict__ E,    // [128][128]
    const __hip_bfloat16* __restrict__ WiT,  // [2][2048][256]
    const float* __restrict__ bF,
    const float* __restrict__ bB,
    float* __restrict__ G)                   // [4][128][512][4]
{
    int dh = blockIdx.x >> 6;
    int dir = dh >> 1, half = dh & 1;
    int m0 = ((blockIdx.x >> 5) & 1) * 64;
    int n0 = (blockIdx.x & 31) * 64;
    int lane = threadIdx.x & 63, wid = threadIdx.x >> 6;
    int wrow = wid >> 1, wcol = wid & 1;
    int r16 = lane & 15, quad = lane >> 4;

    f32x4 acc[2][2] = {};
    const __hip_bfloat16* Ap = E + (size_t)(m0 + wrow * 32 + r16) * 128 + quad * 8;
    const __hip_bfloat16* Bp = WiT + (size_t)dir * 2048 * 256
                             + (size_t)(n0 + wcol * 32 + r16) * 256 + half * 128 + quad * 8;
#pragma unroll
    for (int kb = 0; kb < 128; kb += 32) {
        bf16x8 a0 = *(const bf16x8*)(Ap + kb);
        bf16x8 a1 = *(const bf16x8*)(Ap + 16 * 128 + kb);
        bf16x8 b0 = *(const bf16x8*)(Bp + kb);
        bf16x8 b1 = *(const bf16x8*)(Bp + 16 * 256 + kb);
        acc[0][0] = mfma16(a0, b0, acc[0][0]);
        acc[0][1] = mfma16(a0, b1, acc[0][1]);
        acc[1][0] = mfma16(a1, b0, acc[1][0]);
        acc[1][1] = mfma16(a1, b1, acc[1][1]);
    }
    const float* bias = dir ? bB : bF;
    float* Gt = G + (size_t)dh * 128 * 2048;
#pragma unroll
    for (int rt = 0; rt < 2; rt++)
#pragma unroll
        for (int ct = 0; ct < 2; ct++)
#pragma unroll
            for (int r = 0; r < 4; r++) {
                int mm = m0 + wrow * 32 + rt * 16 + quad * 4 + r;
                int j = n0 + wcol * 32 + ct * 16 + r16;
                float v = acc[rt][ct][r];
                if (half == 0) v += bias[j];
                int g = j >> 9, u = j & 511;
                Gt[((size_t)mm * 512 + u) * 4 + g] = v;
            }
}

// ---------------- prep: VX[t][j] = field_emb @ v_Wi + v_b --------------------
__global__ __launch_bounds__(256) void kprep_vx(
    const __hip_bfloat16* __restrict__ fe,    // [32][1024]
    const __hip_bfloat16* __restrict__ vWiT,  // [4096][1024]
    const float* __restrict__ vb,             // [4096]
    float* __restrict__ VX)                   // [32][4096]
{
    int n0 = blockIdx.x * 128;
    int lane = threadIdx.x & 63, wid = threadIdx.x >> 6;
    int r16 = lane & 15, quad = lane >> 4;
    f32x4 acc[2][2] = {};
    const __hip_bfloat16* Ap = fe + (size_t)r16 * 1024 + quad * 8;
    const __hip_bfloat16* Bp = vWiT + (size_t)(n0 + wid * 32 + r16) * 1024 + quad * 8;
    for (int kb = 0; kb < 1024; kb += 32) {
        bf16x8 a0 = *(const bf16x8*)(Ap + kb);
        bf16x8 a1 = *(const bf16x8*)(Ap + 16 * 1024 + kb);
        bf16x8 b0 = *(const bf16x8*)(Bp + kb);
        bf16x8 b1 = *(const bf16x8*)(Bp + 16 * 1024 + kb);
        acc[0][0] = mfma16(a0, b0, acc[0][0]);
        acc[0][1] = mfma16(a0, b1, acc[0][1]);
        acc[1][0] = mfma16(a1, b0, acc[1][0]);
        acc[1][1] = mfma16(a1, b1, acc[1][1]);
    }
#pragma unroll
    for (int rt = 0; rt < 2; rt++)
#pragma unroll
        for (int ct = 0; ct < 2; ct++)
#pragma unroll
            for (int r = 0; r < 4; r++) {
                int m = rt * 16 + quad * 4 + r;
                int j = n0 + wid * 32 + ct * 16 + r16;
                VX[(size_t)m * 4096 + j] = acc[rt][ct][r] + vb[j];
            }
}

// ======== encoder LSTM step: 512 blocks (dir x 32 mt x 8 us), 32m x 64u ======
__global__ __launch_bounds__(256, 2) void kenc_step(
    int t,
    const __hip_bfloat16* __restrict__ WhT,   // [2][2048][512]
    const float* __restrict__ Gtab,           // [4][128][512][4]
    const int* __restrict__ exs,
    const int* __restrict__ cls,
    const __hip_bfloat16* __restrict__ h_in,  // [2][1024][512]
    __hip_bfloat16* __restrict__ h_out,
    float* __restrict__ c_st,                 // [2][1024][512]
    unsigned char* __restrict__ ctx8)         // [64][256][4][1024] fp8 (x16)
{
    __shared__ __align__(16) __hip_bfloat16 sA[2][32 * 64];
    __shared__ __align__(16) __hip_bfloat16 sB[2][256 * 64];

    int bid = blockIdx.x;
    int dir = bid >> 8;
    int mt  = (bid >> 3) & 31;
    int us  = bid & 7;
    int l = dir ? (63 - t) : t;
    int m0 = mt * 32, u0 = us * 64;

    int lane = threadIdx.x & 63, w = threadIdx.x >> 6;
    int r16 = lane & 15, quad = lane >> 4;
    int srow = lane >> 3, scol = (lane & 7) * 8;   // 8 rows per glds16 call

    const __hip_bfloat16* Ab = h_in + (size_t)dir * 1024 * 512;
    const __hip_bfloat16* Bb = WhT + (size_t)dir * 2048 * 512;

    f32x4 acc[4][2] = {};  // [gate][mi]

    auto stage = [&](int buf, int it) {
        int kb = it * 64;
        glds16(Ab + (size_t)(m0 + w * 8 + srow) * 512 + kb + scol,
               &sA[buf][(w * 8) * 64]);
#pragma unroll
        for (int c = 0; c < 8; c++) {
            int rl = w * 64 + c * 8;
            int rr = rl + srow;
            int g = rr >> 6, j = rr & 63;
            glds16(Bb + (size_t)(g * 512 + u0 + j) * 512 + kb + scol,
                   &sB[buf][rl * 64]);
        }
    };

    stage(0, 0);
    __syncthreads();
    int buf = 0;
    const int NIT = 8;  // 512/64
    for (int it = 0; it < NIT; it++) {
        if (it + 1 < NIT) stage(buf ^ 1, it + 1);
#pragma unroll
        for (int k32 = 0; k32 < 64; k32 += 32) {
            bf16x8 a[2], bf[4];
#pragma unroll
            for (int mi = 0; mi < 2; mi++)
                a[mi] = *(const bf16x8*)&sA[buf][(mi * 16 + r16) * 64 + k32 + quad * 8];
#pragma unroll
            for (int g = 0; g < 4; g++)
                bf[g] = *(const bf16x8*)&sB[buf][(g * 64 + w * 16 + r16) * 64 + k32 + quad * 8];
#pragma unroll
            for (int g = 0; g < 4; g++)
#pragma unroll
                for (int mi = 0; mi < 2; mi++)
                    acc[g][mi] = mfma16(a[mi], bf[g], acc[g][mi]);
        }
        __syncthreads();
        buf ^= 1;
    }

    // epilogue: thread owns u = u0 + w*16 + r16, 8 m's
    int u = u0 + w * 16 + r16;
    size_t cbase = (size_t)dir * 1024 * 512;
    const float* GeT = Gtab + (size_t)(dir * 2) * 128 * 2048;
    const float* GcT = GeT + 128 * 2048;
#pragma unroll
    for (int mi = 0; mi < 2; mi++)
#pragma unroll
        for (int r = 0; r < 4; r++) {
            int m = m0 + mi * 16 + quad * 4 + r;
            int vE = exs[l * 1024 + m], vC = cls[l * 1024 + m];
            f32x4 ge = *(const f32x4*)&GeT[((size_t)vE * 512 + u) * 4];
            f32x4 gc = *(const f32x4*)&GcT[((size_t)vC * 512 + u) * 4];
            float gi = acc[0][mi][r] + ge[0] + gc[0];
            float gf = acc[1][mi][r] + ge[1] + gc[1];
            float gg = acc[2][mi][r] + ge[2] + gc[2];
            float go = acc[3][mi][r] + ge[3] + gc[3];
            size_t cix = cbase + (size_t)m * 512 + u;
            float cn = sigm(gf) * c_st[cix] + sigm(gi) * tanh_f(gg);
            c_st[cix] = cn;
            float hn = sigm(go) * tanh_f(cn);
            h_out[cix] = __float2bfloat16(hn);
            ctx8[(((size_t)l * 256 + (m >> 2)) * 4 + (m & 3)) * 1024 + dir * 512 + u]
                = f32_to_fp8(hn * 16.0f);
        }
}

// ======== decoder fused GEMM: cell (0..127: 32m x 64u) + q (128..255) ========
__global__ __launch_bounds__(256, 2) void kdec_gemm(
    int t,
    const __hip_bfloat16* __restrict__ vWhT,   // [4096][1024]
    const __hip_bfloat16* __restrict__ WattnT, // [1024][1024]
    const float* __restrict__ VX,              // [32][4096]
    const __hip_bfloat16* __restrict__ h_in,   // [256][1024]  (h_t)
    __hip_bfloat16* __restrict__ h_out,        // [256][1024]  (h_{t+1})
    float* __restrict__ c_st,                  // [256][1024]
    float* __restrict__ qout)                  // [256][1024]  (q_t)
{
    __shared__ __align__(16) __hip_bfloat16 sA[2][32 * 64];
    __shared__ __align__(16) __hip_bfloat16 sB[2][256 * 64];

    int bid = blockIdx.x;
    int lane = threadIdx.x & 63, w = threadIdx.x >> 6;
    int r16 = lane & 15, quad = lane >> 4;
    int srow = lane >> 3, scol = (lane & 7) * 8;
    const int NIT = 16;  // 1024/64

    if (bid < 128) {
        int m0 = (bid >> 4) * 32, u0 = (bid & 15) * 64;
        f32x4 acc[4][2] = {};
        auto stage = [&](int buf, int it) {
            int kb = it * 64;
            glds16(h_in + (size_t)(m0 + w * 8 + srow) * 1024 + kb + scol,
                   &sA[buf][(w * 8) * 64]);
#pragma unroll
            for (int c = 0; c < 8; c++) {
                int rl = w * 64 + c * 8;
                int rr = rl + srow;
                int g = rr >> 6, j = rr & 63;
                glds16(vWhT + (size_t)(g * 1024 + u0 + j) * 1024 + kb + scol,
                       &sB[buf][rl * 64]);
            }
        };
        stage(0, 0);
        __syncthreads();
        int buf = 0;
        for (int it = 0; it < NIT; it++) {
            if (it + 1 < NIT) stage(buf ^ 1, it + 1);
#pragma unroll
            for (int k32 = 0; k32 < 64; k32 += 32) {
                bf16x8 a[2], bf[4];
#pragma unroll
                for (int mi = 0; mi < 2; mi++)
                    a[mi] = *(const bf16x8*)&sA[buf][(mi * 16 + r16) * 64 + k32 + quad * 8];
#pragma unroll
                for (int g = 0; g < 4; g++)
                    bf[g] = *(const bf16x8*)&sB[buf][(g * 64 + w * 16 + r16) * 64 + k32 + quad * 8];
#pragma unroll
                for (int g = 0; g < 4; g++)
#pragma unroll
                    for (int mi = 0; mi < 2; mi++)
                        acc[g][mi] = mfma16(a[mi], bf[g], acc[g][mi]);
            }
            __syncthreads();
            buf ^= 1;
        }
        int u = u0 + w * 16 + r16;
        const float* vx = VX + (size_t)t * 4096;
        float v0 = vx[u], v1 = vx[1024 + u], v2 = vx[2048 + u], v3 = vx[3072 + u];
#pragma unroll
        for (int mi = 0; mi < 2; mi++)
#pragma unroll
            for (int r = 0; r < 4; r++) {
                int m = m0 + mi * 16 + quad * 4 + r;
                float gi = acc[0][mi][r] + v0;
                float gf = acc[1][mi][r] + v1;
                float gg = acc[2][mi][r] + v2;
                float go = acc[3][mi][r] + v3;
                size_t cix = (size_t)m * 1024 + u;
                float cn = sigm(gf) * c_st[cix] + sigm(gi) * tanh_f(gg);
                c_st[cix] = cn;
                h_out[cix] = __float2bfloat16(sigm(go) * tanh_f(cn));
            }
    } else {
        int b2 = bid - 128;
        int m0 = (b2 >> 4) * 32, n0 = (b2 & 15) * 64;
        f32x4 acc[2] = {};
        auto stage = [&](int buf, int it) {
            int kb = it * 64;
            glds16(h_in + (size_t)(m0 + w * 8 + srow) * 1024 + kb + scol,
                   &sA[buf][(w * 8) * 64]);
#pragma unroll
            for (int c = 0; c < 2; c++) {
                int rl = w * 16 + c * 8;
                glds16(WattnT + (size_t)(n0 + rl + srow) * 1024 + kb + scol,
                       &sB[buf][rl * 64]);
            }
        };
        stage(0, 0);
        __syncthreads();
        int buf = 0;
        for (int it = 0; it < NIT; it++) {
            if (it + 1 < NIT) stage(buf ^ 1, it + 1);
#pragma unroll
            for (int k32 = 0; k32 < 64; k32 += 32) {
                bf16x8 a[2];
#pragma unroll
                for (int mi = 0; mi < 2; mi++)
                    a[mi] = *(const bf16x8*)&sA[buf][(mi * 16 + r16) * 64 + k32 + quad * 8];
                bf16x8 bf = *(const bf16x8*)&sB[buf][(w * 16 + r16) * 64 + k32 + quad * 8];
#pragma unroll
                for (int mi = 0; mi < 2; mi++)
                    acc[mi] = mfma16(a[mi], bf, acc[mi]);
            }
            __syncthreads();
            buf ^= 1;
        }
        int n = n0 + w * 16 + r16;
#pragma unroll
        for (int mi = 0; mi < 2; mi++)
#pragma unroll
            for (int r = 0; r < 4; r++) {
                int m = m0 + mi * 16 + quad * 4 + r;
                qout[(size_t)m * 1024 + n] = acc[mi][r];
            }
    }
}

// ======== attention: fp8 ctx, no-max exp (scores O(1)), 4-deep pipeline ======
// wave (n, lq): io-example n, rows l = lq*16 .. lq*16+15. Merge = plain sum.
__global__ __launch_bounds__(1024, 1) void kattn(
    int t,
    const float* __restrict__ q,              // [256][1024]
    const unsigned char* __restrict__ ctx8,   // [64][256][4][1024] fp8 (x16)
    const __hip_bfloat16* __restrict__ hcur,  // [256][1024]
    const __hip_bfloat16* __restrict__ WcT,   // [64][2048]
    const float* __restrict__ bcomp,          // [64]
    const int* __restrict__ actions,          // [256][32]
    float* __restrict__ nll)                  // [256]
{
    __shared__ float scacc[16][64 * 17];      // stride-17: conflict-free
    __shared__ float sS[4][4];
    __shared__ float spool[1024];
    __shared__ float shb[1024];
    __shared__ float slg[64];

    int b = blockIdx.x;
    int tid = threadIdx.x;
    int lane = tid & 63, wid = tid >> 6;
    int n = wid & 3, lq = wid >> 2;

    float qr[16];
    {
        const float* qp = q + (size_t)b * 1024 + lane * 16;
#pragma unroll
        for (int i = 0; i < 16; i++) qr[i] = qp[i] * 0.0625f;  // fold 1/16 fp8 scale
    }

    const size_t LSTR = 1024 * 1024;          // ctx8 l-stride bytes
    const unsigned char* cb = ctx8 + ((size_t)b * 4 + n) * 1024 + lane * 16
                            + (size_t)(lq * 16) * LSTR;

    float ssum = 0.f;
    float cacc[16];
#pragma unroll
    for (int i = 0; i < 16; i++) cacc[i] = 0.f;

    u32x4 rw[4];
#pragma unroll
    for (int j = 0; j < 4; j++)
        rw[j] = __builtin_nontemporal_load((const u32x4*)(cb + (size_t)j * LSTR));

#pragma unroll
    for (int j = 0; j < 16; j++) {
        u32x4 wv = rw[j & 3];
        if (j + 4 < 16)
            rw[j & 3] = __builtin_nontemporal_load(
                (const u32x4*)(cb + (size_t)(j + 4) * LSTR));
        float rv[16];
        fp8x4_to_f32(wv[0], rv);
        fp8x4_to_f32(wv[1], rv + 4);
        fp8x4_to_f32(wv[2], rv + 8);
        fp8x4_to_f32(wv[3], rv + 12);
        float d = 0.f;
#pragma unroll
        for (int i = 0; i < 16; i++) d += rv[i] * qr[i];
        d = wsum(d);
        float p = __expf(fminf(d, 60.f));   // scores O(1): max-free softmax
        ssum += p;
#pragma unroll
        for (int i = 0; i < 16; i++) cacc[i] += p * rv[i];
    }

#pragma unroll
    for (int i = 0; i < 16; i++) scacc[wid][lane * 17 + i] = cacc[i];
    if (lane == 0) sS[n][lq] = ssum;
    shb[tid] = __bfloat162float(hcur[(size_t)b * 1024 + tid]);
    __syncthreads();

    // merge 4 l-chunks per n (plain sums), normalize (1/16 scale), max-pool
    {
        int eo = (tid >> 4) * 17 + (tid & 15);
        float pool = -1e30f;
#pragma unroll
        for (int nn = 0; nn < 4; nn++) {
            float S = sS[nn][0] + sS[nn][1] + sS[nn][2] + sS[nn][3];
            float V = scacc[nn * 4 + 0][eo] + scacc[nn * 4 + 1][eo]
                    + scacc[nn * 4 + 2][eo] + scacc[nn * 4 + 3][eo];
            pool = fmaxf(pool, V / (16.0f * S));
        }
        spool[tid] = pool;
    }
    __syncthreads();

    // logits: wave wid computes prods wid*4 .. wid*4+3
#pragma unroll
    for (int pi = 0; pi < 4; pi++) {
        int p = wid * 4 + pi;
        const __hip_bfloat16* wr = WcT + (size_t)p * 2048;
        float s = 0.f;
#pragma unroll
        for (int jj = 0; jj < 16; jj++) {
            int e = lane + jj * 64;
            s += shb[e] * __bfloat162float(wr[e]);
            s += spool[e] * __bfloat162float(wr[1024 + e]);
        }
        s = wsum(s);
        if (lane == 0) slg[p] = s + bcomp[p];
    }
    __syncthreads();
    if (tid < 64) {
        float v = slg[tid];
        float m2 = wmaxr(v);
        float se = wsum(__expf(v - m2));
        int a = actions[b * 32 + t];
        if (tid == a) nll[b] -= (v - m2 - __logf(se));
    }
}

// ---------------- decoder init: max-pool final states over io examples -------
__global__ __launch_bounds__(256) void kinit_dec(
    const __hip_bfloat16* __restrict__ hf,  // final h (buf0): [2][1024][512]
    const float* __restrict__ cf,
    __hip_bfloat16* __restrict__ h0,        // [256][1024]
    float* __restrict__ c0)
{
    int idx = blockIdx.x * 256 + threadIdx.x;
    int b = idx >> 10, e = idx & 1023;
    int dir = e >> 9, u = e & 511;
    const __hip_bfloat16* hs = hf + (size_t)dir * 1024 * 512;
    const float* cs = cf + (size_t)dir * 1024 * 512;
    float hv = -3.4e38f, cv = -3.4e38f;
#pragma unroll
    for (int n = 0; n < 4; n++) {
        size_t ix = (size_t)(b * 4 + n) * 512 + u;
        hv = fmaxf(hv, __bfloat162float(hs[ix]));
        cv = fmaxf(cv, cs[ix]);
    }
    h0[idx] = __float2bfloat16(hv);
    c0[idx] = cv;
}

__global__ void kfinal(const float* __restrict__ nll, void* __restrict__ out,
                       const int* __restrict__ mode) {
    int i = threadIdx.x;
    if (*mode) ((__hip_bfloat16*)out)[i] = __float2bfloat16(nll[i]);
    else       ((float*)out)[i] = nll[i];
}

// -----------------------------------------------------------------------------
extern "C" void kernel_launch(void* const* d_in, const int* in_sizes, int n_in,
                              void* d_out, int out_size, void* d_ws, size_t ws_size,
                              hipStream_t stream) {
    const int* exs = (const int*)d_in[0];
    const int* cls = (const int*)d_in[1];
    const void* E_raw     = d_in[2];
    const void* WiF_raw   = d_in[3];
    const void* WhF_raw   = d_in[4];
    const void* bF_raw    = d_in[5];
    const void* WiB_raw   = d_in[6];
    const void* WhB_raw   = d_in[7];
    const void* bB_raw    = d_in[8];
    const void* Wattn_raw = d_in[9];
    const void* Wcomp_raw = d_in[10];
    const void* bcomp_raw = d_in[11];
    const void* vWi_raw   = d_in[12];
    const void* vWh_raw   = d_in[13];
    const void* vb_raw    = d_in[14];
    const void* fe_raw    = d_in[15];
    const int* actions = (const int*)d_in[16];
    (void)in_sizes; (void)n_in; (void)out_size; (void)ws_size;

    char* w = (char*)d_ws;
    size_t off = 0;
    auto take = [&](size_t bytes) -> char* {
        char* p = w + off;
        off = (off + bytes + 255) & ~(size_t)255;
        return p;
    };
    __hip_bfloat16* WhT    = (__hip_bfloat16*)take(2ull * 2048 * 512 * 2);
    __hip_bfloat16* WiT    = (__hip_bfloat16*)take(2ull * 2048 * 256 * 2);
    __hip_bfloat16* vWhT   = (__hip_bfloat16*)take(4096ull * 1024 * 2);
    __hip_bfloat16* vWiT   = (__hip_bfloat16*)take(4096ull * 1024 * 2);
    __hip_bfloat16* WattnT = (__hip_bfloat16*)take(1024ull * 1024 * 2);
    __hip_bfloat16* WcT    = (__hip_bfloat16*)take(64ull * 2048 * 2);
    __hip_bfloat16* Ebf    = (__hip_bfloat16*)take(128ull * 128 * 2);
    __hip_bfloat16* febf   = (__hip_bfloat16*)take(32ull * 1024 * 2);
    float* bFf   = (float*)take(2048 * 4);
    float* bBf   = (float*)take(2048 * 4);
    float* bcf   = (float*)take(64 * 4);
    float* vbf   = (float*)take(4096 * 4);
    float* Gtab  = (float*)take(4ull * 128 * 2048 * 4);
    float* VX    = (float*)take(32ull * 4096 * 4);
    __hip_bfloat16* hEnc = (__hip_bfloat16*)take(2ull * 2 * 1024 * 512 * 2); // [buf][dir][1024][512]
    float* cEnc = (float*)take(2ull * 1024 * 512 * 4);
    __hip_bfloat16* hDec = (__hip_bfloat16*)take(2ull * 256 * 1024 * 2);
    float* cDec = (float*)take(256ull * 1024 * 4);
    float* qbuf = (float*)take(256ull * 1024 * 4);
    float* nll  = (float*)take(256 * 4);
    int*   mode = (int*)take(256);
    unsigned char* ctx8 = (unsigned char*)take(64ull * 1024 * 1024);  // fp8 [64][256][4][1024]

    (void)hipMemsetAsync(hEnc, 0, 2ull * 1024 * 512 * 2, stream);  // h buf0, both dirs
    (void)hipMemsetAsync(cEnc, 0, 2ull * 1024 * 512 * 4, stream);
    (void)hipMemsetAsync(nll, 0, 256 * 4, stream);

    kdetect<<<1, 128, 0, stream>>>((const unsigned int*)E_raw, mode);

    kcvt_bf16<<<64, 256, 0, stream>>>(E_raw,  Ebf,  128 * 128, mode);
    kcvt_bf16<<<128, 256, 0, stream>>>(fe_raw, febf, 32 * 1024, mode);
    kcvt_f32<<<8, 256, 0, stream>>>(bF_raw, bFf, 2048, mode);
    kcvt_f32<<<8, 256, 0, stream>>>(bB_raw, bBf, 2048, mode);
    kcvt_f32<<<1, 256, 0, stream>>>(bcomp_raw, bcf, 64, mode);
    kcvt_f32<<<16, 256, 0, stream>>>(vb_raw, vbf, 4096, mode);

    ktranspose_cvt<<<dim3(32, 8),  256, 0, stream>>>(WhF_raw,   WhT,              512, 2048, mode);
    ktranspose_cvt<<<dim3(32, 8),  256, 0, stream>>>(WhB_raw,   WhT + 2048 * 512, 512, 2048, mode);
    ktranspose_cvt<<<dim3(32, 4),  256, 0, stream>>>(WiF_raw,   WiT,              256, 2048, mode);
    ktranspose_cvt<<<dim3(32, 4),  256, 0, stream>>>(WiB_raw,   WiT + 2048 * 256, 256, 2048, mode);
    ktranspose_cvt<<<dim3(64, 16), 256, 0, stream>>>(vWh_raw,   vWhT,            1024, 4096, mode);
    ktranspose_cvt<<<dim3(64, 16), 256, 0, stream>>>(vWi_raw,   vWiT,            1024, 4096, mode);
    ktranspose_cvt<<<dim3(16, 16), 256, 0, stream>>>(Wattn_raw, WattnT,          1024, 1024, mode);
    ktranspose_cvt<<<dim3(1, 32),  256, 0, stream>>>(Wcomp_raw, WcT,             2048, 64,   mode);

    kprep_gtab<<<256, 256, 0, stream>>>(Ebf, WiT, bFf, bBf, Gtab);
    kprep_vx<<<32, 256, 0, stream>>>(febf, vWiT, vbf, VX);

    const size_t HB = 2ull * 1024 * 512;
    for (int t = 0; t < 64; t++) {
        kenc_step<<<512, 256, 0, stream>>>(t, WhT, Gtab, exs, cls,
                                           hEnc + (size_t)(t & 1) * HB,
                                           hEnc + (size_t)((t + 1) & 1) * HB,
                                           cEnc, ctx8);
    }
    kinit_dec<<<1024, 256, 0, stream>>>(hEnc, cEnc, hDec, cDec);

    const size_t HD = 256ull * 1024;
    for (int t = 0; t < 32; t++) {
        const __hip_bfloat16* hcur = hDec + (size_t)(t & 1) * HD;
        kdec_gemm<<<256, 256, 0, stream>>>(t, vWhT, WattnT, VX, hcur,
                                           hDec + (size_t)((t + 1) & 1) * HD, cDec, qbuf);
        kattn<<<256, 1024, 0, stream>>>(t, qbuf, ctx8, hcur, WcT, bcf, actions, nll);
    }
    kfinal<<<1, 256, 0, stream>>>(nll, d_out, mode);
}

// Round 7
// 3016.050 us; speedup vs baseline: 2.1338x; 1.7738x over previous
//
#include <hip/hip_runtime.h>
#include <hip/hip_bf16.h>

typedef __bf16 bf16x8 __attribute__((ext_vector_type(8)));
typedef float  f32x4  __attribute__((ext_vector_type(4)));
typedef float  f32x2  __attribute__((ext_vector_type(2)));
typedef unsigned int u32x4 __attribute__((ext_vector_type(4)));
typedef unsigned short ushort_t;
static_assert(sizeof(bf16x8) == 16, "bf16x8 must be 16B");

#define DEV __device__ __forceinline__

DEV f32x4 mfma16(bf16x8 a, bf16x8 b, f32x4 c) {
    return __builtin_amdgcn_mfma_f32_16x16x32_bf16(a, b, c, 0, 0, 0);
}
DEV float wsum(float v) {
#pragma unroll
    for (int o = 32; o > 0; o >>= 1) v += __shfl_xor(v, o, 64);
    return v;
}
DEV float wmaxr(float v) {
#pragma unroll
    for (int o = 32; o > 0; o >>= 1) v = fmaxf(v, __shfl_xor(v, o, 64));
    return v;
}
DEV float sigm(float x)   { return 1.0f / (1.0f + __expf(-x)); }
DEV float tanh_f(float x) { return 2.0f / (1.0f + __expf(-2.0f * x)) - 1.0f; }

// async global->LDS, 16B per lane; lds dest must be wave-uniform base (+lane*16)
DEV void glds16(const __hip_bfloat16* g, __hip_bfloat16* l) {
    __builtin_amdgcn_global_load_lds(
        (const __attribute__((address_space(1))) unsigned int*)g,
        (__attribute__((address_space(3))) unsigned int*)l, 16, 0, 0);
}

DEV unsigned char f32_to_fp8(float v) {
    int p = __builtin_amdgcn_cvt_pk_fp8_f32(v, v, 0, false);
    return (unsigned char)(p & 0xFF);
}
DEV void fp8x4_to_f32(unsigned int w, float* out) {
    f32x2 lo = __builtin_amdgcn_cvt_pk_f32_fp8(w, false);
    f32x2 hi = __builtin_amdgcn_cvt_pk_f32_fp8(w, true);
    out[0] = lo[0]; out[1] = lo[1]; out[2] = hi[0]; out[3] = hi[1];
}

// ---------------- dtype detection: 1 = inputs are bf16, 0 = inputs are fp32 --
__global__ __launch_bounds__(128) void kdetect(const unsigned int* __restrict__ raw,
                                               int* __restrict__ mode) {
    __shared__ int cnt;
    if (threadIdx.x == 0) cnt = 0;
    __syncthreads();
    unsigned int w = raw[threadIdx.x];
    unsigned short lo = (unsigned short)(w & 0xFFFFu);
    unsigned int f32bits = ((unsigned int)lo) << 16;
    float v;
    __builtin_memcpy(&v, &f32bits, 4);
    float a = fabsf(v);
    if (a >= 1e-4f && a <= 1.0f) atomicAdd(&cnt, 1);
    __syncthreads();
    if (threadIdx.x == 0) *mode = (cnt >= 64) ? 1 : 0;
}

__global__ __launch_bounds__(256) void kcvt_bf16(const void* __restrict__ src,
                                                 __hip_bfloat16* __restrict__ dst,
                                                 int n, const int* __restrict__ mode) {
    int i = blockIdx.x * 256 + threadIdx.x;
    if (i >= n) return;
    if (*mode) dst[i] = ((const __hip_bfloat16*)src)[i];
    else       dst[i] = __float2bfloat16(((const float*)src)[i]);
}

__global__ __launch_bounds__(256) void kcvt_f32(const void* __restrict__ src,
                                                float* __restrict__ dst,
                                                int n, const int* __restrict__ mode) {
    int i = blockIdx.x * 256 + threadIdx.x;
    if (i >= n) return;
    if (*mode) dst[i] = __bfloat162float(((const __hip_bfloat16*)src)[i]);
    else       dst[i] = ((const float*)src)[i];
}

// --------- tiled transpose + convert: out_bf16[c][r] = (bf16)in[r][c] --------
__global__ __launch_bounds__(256) void ktranspose_cvt(const void* __restrict__ src,
                                                      __hip_bfloat16* __restrict__ out,
                                                      int R, int C,
                                                      const int* __restrict__ mode) {
    __shared__ float tile[64][65];
    int c0 = blockIdx.x * 64, r0 = blockIdx.y * 64;
    int tx = threadIdx.x & 63, ty = threadIdx.x >> 6;
    int m = *mode;
#pragma unroll
    for (int i = ty; i < 64; i += 4) {
        size_t ix = (size_t)(r0 + i) * C + (c0 + tx);
        tile[i][tx] = m ? __bfloat162float(((const __hip_bfloat16*)src)[ix])
                        : ((const float*)src)[ix];
    }
    __syncthreads();
#pragma unroll
    for (int i = ty; i < 64; i += 4)
        out[(size_t)(c0 + i) * R + (r0 + tx)] = __float2bfloat16(tile[tx][i]);
}

// ------ prep: G tables, gate-interleaved: G[dh][v][u<512][g<4] = E@Wi (+b) ---
__global__ __launch_bounds__(256) void kprep_gtab(
    const __hip_bfloat16* __restrict__ E,    // [128][128]
    const __hip_bfloat16* __restrict__ WiT,  // [2][2048][256]
    const float* __restrict__ bF,
    const float* __restrict__ bB,
    float* __restrict__ G)                   // [4][128][512][4]
{
    int dh = blockIdx.x >> 6;
    int dir = dh >> 1, half = dh & 1;
    int m0 = ((blockIdx.x >> 5) & 1) * 64;
    int n0 = (blockIdx.x & 31) * 64;
    int lane = threadIdx.x & 63, wid = threadIdx.x >> 6;
    int wrow = wid >> 1, wcol = wid & 1;
    int r16 = lane & 15, quad = lane >> 4;

    f32x4 acc[2][2] = {};
    const __hip_bfloat16* Ap = E + (size_t)(m0 + wrow * 32 + r16) * 128 + quad * 8;
    const __hip_bfloat16* Bp = WiT + (size_t)dir * 2048 * 256
                             + (size_t)(n0 + wcol * 32 + r16) * 256 + half * 128 + quad * 8;
#pragma unroll
    for (int kb = 0; kb < 128; kb += 32) {
        bf16x8 a0 = *(const bf16x8*)(Ap + kb);
        bf16x8 a1 = *(const bf16x8*)(Ap + 16 * 128 + kb);
        bf16x8 b0 = *(const bf16x8*)(Bp + kb);
        bf16x8 b1 = *(const bf16x8*)(Bp + 16 * 256 + kb);
        acc[0][0] = mfma16(a0, b0, acc[0][0]);
        acc[0][1] = mfma16(a0, b1, acc[0][1]);
        acc[1][0] = mfma16(a1, b0, acc[1][0]);
        acc[1][1] = mfma16(a1, b1, acc[1][1]);
    }
    const float* bias = dir ? bB : bF;
    float* Gt = G + (size_t)dh * 128 * 2048;
#pragma unroll
    for (int rt = 0; rt < 2; rt++)
#pragma unroll
        for (int ct = 0; ct < 2; ct++)
#pragma unroll
            for (int r = 0; r < 4; r++) {
                int mm = m0 + wrow * 32 + rt * 16 + quad * 4 + r;
                int j = n0 + wcol * 32 + ct * 16 + r16;
                float v = acc[rt][ct][r];
                if (half == 0) v += bias[j];
                int g = j >> 9, u = j & 511;
                Gt[((size_t)mm * 512 + u) * 4 + g] = v;
            }
}

// ---------------- prep: VX[t][j] = field_emb @ v_Wi + v_b --------------------
__global__ __launch_bounds__(256) void kprep_vx(
    const __hip_bfloat16* __restrict__ fe,    // [32][1024]
    const __hip_bfloat16* __restrict__ vWiT,  // [4096][1024]
    const float* __restrict__ vb,             // [4096]
    float* __restrict__ VX)                   // [32][4096]
{
    int n0 = blockIdx.x * 128;
    int lane = threadIdx.x & 63, wid = threadIdx.x >> 6;
    int r16 = lane & 15, quad = lane >> 4;
    f32x4 acc[2][2] = {};
    const __hip_bfloat16* Ap = fe + (size_t)r16 * 1024 + quad * 8;
    const __hip_bfloat16* Bp = vWiT + (size_t)(n0 + wid * 32 + r16) * 1024 + quad * 8;
    for (int kb = 0; kb < 1024; kb += 32) {
        bf16x8 a0 = *(const bf16x8*)(Ap + kb);
        bf16x8 a1 = *(const bf16x8*)(Ap + 16 * 1024 + kb);
        bf16x8 b0 = *(const bf16x8*)(Bp + kb);
        bf16x8 b1 = *(const bf16x8*)(Bp + 16 * 1024 + kb);
        acc[0][0] = mfma16(a0, b0, acc[0][0]);
        acc[0][1] = mfma16(a0, b1, acc[0][1]);
        acc[1][0] = mfma16(a1, b0, acc[1][0]);
        acc[1][1] = mfma16(a1, b1, acc[1][1]);
    }
#pragma unroll
    for (int rt = 0; rt < 2; rt++)
#pragma unroll
        for (int ct = 0; ct < 2; ct++)
#pragma unroll
            for (int r = 0; r < 4; r++) {
                int m = rt * 16 + quad * 4 + r;
                int j = n0 + wid * 32 + ct * 16 + r16;
                VX[(size_t)m * 4096 + j] = acc[rt][ct][r] + vb[j];
            }
}

// ======== encoder LSTM step: 512 blocks (dir x 32 mt x 8 us), 32m x 64u ======
__global__ __launch_bounds__(256, 2) void kenc_step(
    int t,
    const __hip_bfloat16* __restrict__ WhT,   // [2][2048][512]
    const float* __restrict__ Gtab,           // [4][128][512][4]
    const int* __restrict__ exs,
    const int* __restrict__ cls,
    const __hip_bfloat16* __restrict__ h_in,  // [2][1024][512]
    __hip_bfloat16* __restrict__ h_out,
    float* __restrict__ c_st,                 // [2][1024][512]
    unsigned char* __restrict__ ctx8)         // [64][256][4][1024] fp8 (x16)
{
    __shared__ __align__(16) __hip_bfloat16 sA[2][32 * 64];
    __shared__ __align__(16) __hip_bfloat16 sB[2][256 * 64];

    int bid = blockIdx.x;
    int dir = bid >> 8;
    int mt  = (bid >> 3) & 31;
    int us  = bid & 7;
    int l = dir ? (63 - t) : t;
    int m0 = mt * 32, u0 = us * 64;

    int lane = threadIdx.x & 63, w = threadIdx.x >> 6;
    int r16 = lane & 15, quad = lane >> 4;
    int srow = lane >> 3, scol = (lane & 7) * 8;   // 8 rows per glds16 call

    const __hip_bfloat16* Ab = h_in + (size_t)dir * 1024 * 512;
    const __hip_bfloat16* Bb = WhT + (size_t)dir * 2048 * 512;

    f32x4 acc[4][2] = {};  // [gate][mi]

    auto stage = [&](int buf, int it) {
        int kb = it * 64;
        glds16(Ab + (size_t)(m0 + w * 8 + srow) * 512 + kb + scol,
               &sA[buf][(w * 8) * 64]);
#pragma unroll
        for (int c = 0; c < 8; c++) {
            int rl = w * 64 + c * 8;
            int rr = rl + srow;
            int g = rr >> 6, j = rr & 63;
            glds16(Bb + (size_t)(g * 512 + u0 + j) * 512 + kb + scol,
                   &sB[buf][rl * 64]);
        }
    };

    stage(0, 0);
    __syncthreads();
    int buf = 0;
    const int NIT = 8;  // 512/64
    for (int it = 0; it < NIT; it++) {
        if (it + 1 < NIT) stage(buf ^ 1, it + 1);
#pragma unroll
        for (int k32 = 0; k32 < 64; k32 += 32) {
            bf16x8 a[2], bf[4];
#pragma unroll
            for (int mi = 0; mi < 2; mi++)
                a[mi] = *(const bf16x8*)&sA[buf][(mi * 16 + r16) * 64 + k32 + quad * 8];
#pragma unroll
            for (int g = 0; g < 4; g++)
                bf[g] = *(const bf16x8*)&sB[buf][(g * 64 + w * 16 + r16) * 64 + k32 + quad * 8];
#pragma unroll
            for (int g = 0; g < 4; g++)
#pragma unroll
                for (int mi = 0; mi < 2; mi++)
                    acc[g][mi] = mfma16(a[mi], bf[g], acc[g][mi]);
        }
        __syncthreads();
        buf ^= 1;
    }

    // epilogue: thread owns u = u0 + w*16 + r16, 8 m's
    int u = u0 + w * 16 + r16;
    size_t cbase = (size_t)dir * 1024 * 512;
    const float* GeT = Gtab + (size_t)(dir * 2) * 128 * 2048;
    const float* GcT = GeT + 128 * 2048;
#pragma unroll
    for (int mi = 0; mi < 2; mi++)
#pragma unroll
        for (int r = 0; r < 4; r++) {
            int m = m0 + mi * 16 + quad * 4 + r;
            int vE = exs[l * 1024 + m], vC = cls[l * 1024 + m];
            f32x4 ge = *(const f32x4*)&GeT[((size_t)vE * 512 + u) * 4];
            f32x4 gc = *(const f32x4*)&GcT[((size_t)vC * 512 + u) * 4];
            float gi = acc[0][mi][r] + ge[0] + gc[0];
            float gf = acc[1][mi][r] + ge[1] + gc[1];
            float gg = acc[2][mi][r] + ge[2] + gc[2];
            float go = acc[3][mi][r] + ge[3] + gc[3];
            size_t cix = cbase + (size_t)m * 512 + u;
            float cn = sigm(gf) * c_st[cix] + sigm(gi) * tanh_f(gg);
            c_st[cix] = cn;
            float hn = sigm(go) * tanh_f(cn);
            h_out[cix] = __float2bfloat16(hn);
            ctx8[(((size_t)l * 256 + (m >> 2)) * 4 + (m & 3)) * 1024 + dir * 512 + u]
                = f32_to_fp8(hn * 16.0f);
        }
}

// ======== decoder fused GEMM: cell (0..127: 32m x 64u) + q (128..255) ========
__global__ __launch_bounds__(256, 2) void kdec_gemm(
    int t,
    const __hip_bfloat16* __restrict__ vWhT,   // [4096][1024]
    const __hip_bfloat16* __restrict__ WattnT, // [1024][1024]
    const float* __restrict__ VX,              // [32][4096]
    const __hip_bfloat16* __restrict__ h_in,   // [256][1024]  (h_t)
    __hip_bfloat16* __restrict__ h_out,        // [256][1024]  (h_{t+1})
    float* __restrict__ c_st,                  // [256][1024]
    float* __restrict__ qout)                  // [256][1024]  (q_t)
{
    __shared__ __align__(16) __hip_bfloat16 sA[2][32 * 64];
    __shared__ __align__(16) __hip_bfloat16 sB[2][256 * 64];

    int bid = blockIdx.x;
    int lane = threadIdx.x & 63, w = threadIdx.x >> 6;
    int r16 = lane & 15, quad = lane >> 4;
    int srow = lane >> 3, scol = (lane & 7) * 8;
    const int NIT = 16;  // 1024/64

    if (bid < 128) {
        int m0 = (bid >> 4) * 32, u0 = (bid & 15) * 64;
        f32x4 acc[4][2] = {};
        auto stage = [&](int buf, int it) {
            int kb = it * 64;
            glds16(h_in + (size_t)(m0 + w * 8 + srow) * 1024 + kb + scol,
                   &sA[buf][(w * 8) * 64]);
#pragma unroll
            for (int c = 0; c < 8; c++) {
                int rl = w * 64 + c * 8;
                int rr = rl + srow;
                int g = rr >> 6, j = rr & 63;
                glds16(vWhT + (size_t)(g * 1024 + u0 + j) * 1024 + kb + scol,
                       &sB[buf][rl * 64]);
            }
        };
        stage(0, 0);
        __syncthreads();
        int buf = 0;
        for (int it = 0; it < NIT; it++) {
            if (it + 1 < NIT) stage(buf ^ 1, it + 1);
#pragma unroll
            for (int k32 = 0; k32 < 64; k32 += 32) {
                bf16x8 a[2], bf[4];
#pragma unroll
                for (int mi = 0; mi < 2; mi++)
                    a[mi] = *(const bf16x8*)&sA[buf][(mi * 16 + r16) * 64 + k32 + quad * 8];
#pragma unroll
                for (int g = 0; g < 4; g++)
                    bf[g] = *(const bf16x8*)&sB[buf][(g * 64 + w * 16 + r16) * 64 + k32 + quad * 8];
#pragma unroll
                for (int g = 0; g < 4; g++)
#pragma unroll
                    for (int mi = 0; mi < 2; mi++)
                        acc[g][mi] = mfma16(a[mi], bf[g], acc[g][mi]);
            }
            __syncthreads();
            buf ^= 1;
        }
        int u = u0 + w * 16 + r16;
        const float* vx = VX + (size_t)t * 4096;
        float v0 = vx[u], v1 = vx[1024 + u], v2 = vx[2048 + u], v3 = vx[3072 + u];
#pragma unroll
        for (int mi = 0; mi < 2; mi++)
#pragma unroll
            for (int r = 0; r < 4; r++) {
                int m = m0 + mi * 16 + quad * 4 + r;
                float gi = acc[0][mi][r] + v0;
                float gf = acc[1][mi][r] + v1;
                float gg = acc[2][mi][r] + v2;
                float go = acc[3][mi][r] + v3;
                size_t cix = (size_t)m * 1024 + u;
                float cn = sigm(gf) * c_st[cix] + sigm(gi) * tanh_f(gg);
                c_st[cix] = cn;
                h_out[cix] = __float2bfloat16(sigm(go) * tanh_f(cn));
            }
    } else {
        int b2 = bid - 128;
        int m0 = (b2 >> 4) * 32, n0 = (b2 & 15) * 64;
        f32x4 acc[2] = {};
        auto stage = [&](int buf, int it) {
            int kb = it * 64;
            glds16(h_in + (size_t)(m0 + w * 8 + srow) * 1024 + kb + scol,
                   &sA[buf][(w * 8) * 64]);
#pragma unroll
            for (int c = 0; c < 2; c++) {
                int rl = w * 16 + c * 8;
                glds16(WattnT + (size_t)(n0 + rl + srow) * 1024 + kb + scol,
                       &sB[buf][rl * 64]);
            }
        };
        stage(0, 0);
        __syncthreads();
        int buf = 0;
        for (int it = 0; it < NIT; it++) {
            if (it + 1 < NIT) stage(buf ^ 1, it + 1);
#pragma unroll
            for (int k32 = 0; k32 < 64; k32 += 32) {
                bf16x8 a[2];
#pragma unroll
                for (int mi = 0; mi < 2; mi++)
                    a[mi] = *(const bf16x8*)&sA[buf][(mi * 16 + r16) * 64 + k32 + quad * 8];
                bf16x8 bf = *(const bf16x8*)&sB[buf][(w * 16 + r16) * 64 + k32 + quad * 8];
#pragma unroll
                for (int mi = 0; mi < 2; mi++)
                    acc[mi] = mfma16(a[mi], bf, acc[mi]);
            }
            __syncthreads();
            buf ^= 1;
        }
        int n = n0 + w * 16 + r16;
#pragma unroll
        for (int mi = 0; mi < 2; mi++)
#pragma unroll
            for (int r = 0; r < 4; r++) {
                int m = m0 + mi * 16 + quad * 4 + r;
                qout[(size_t)m * 1024 + n] = acc[mi][r];
            }
    }
}

// ======== attention: fp8 ctx, no-max exp, 512 thr (8 waves: io n x l-half) ===
__global__ __launch_bounds__(512, 2) void kattn(
    int t,
    const float* __restrict__ q,              // [256][1024]
    const unsigned char* __restrict__ ctx8,   // [64][256][4][1024] fp8 (x16)
    const __hip_bfloat16* __restrict__ hcur,  // [256][1024]
    const __hip_bfloat16* __restrict__ WcT,   // [64][2048]
    const float* __restrict__ bcomp,          // [64]
    const int* __restrict__ actions,          // [256][32]
    float* __restrict__ nll)                  // [256]
{
    __shared__ float scacc[8][64 * 17];       // stride-17, [wid][element]
    __shared__ float sS[4][2];
    __shared__ float spool[1024];
    __shared__ float shb[1024];
    __shared__ float slg[64];

    int b = blockIdx.x;
    int tid = threadIdx.x;
    int lane = tid & 63, wid = tid >> 6;      // 8 waves
    int n = wid >> 1, lh = wid & 1;           // io-example n, l-half lh

    float qr[16];
    {
        const float* qp = q + (size_t)b * 1024 + lane * 16;
#pragma unroll
        for (int i = 0; i < 16; i++) qr[i] = qp[i] * 0.0625f;  // fold 1/16 fp8 scale
    }

    const size_t LSTR = 1024 * 1024;          // ctx8 l-stride bytes
    const unsigned char* cb = ctx8 + ((size_t)b * 4 + n) * 1024 + lane * 16
                            + (size_t)(lh * 32) * LSTR;

    float ssum = 0.f;
    float cacc[16];
#pragma unroll
    for (int i = 0; i < 16; i++) cacc[i] = 0.f;

    u32x4 rw[4];
#pragma unroll
    for (int j = 0; j < 4; j++)
        rw[j] = __builtin_nontemporal_load((const u32x4*)(cb + (size_t)j * LSTR));

    for (int j = 0; j < 32; j++) {
        u32x4 wv = rw[j & 3];
        if (j + 4 < 32)
            rw[j & 3] = __builtin_nontemporal_load(
                (const u32x4*)(cb + (size_t)(j + 4) * LSTR));
        float rv[16];
        fp8x4_to_f32(wv[0], rv);
        fp8x4_to_f32(wv[1], rv + 4);
        fp8x4_to_f32(wv[2], rv + 8);
        fp8x4_to_f32(wv[3], rv + 12);
        float d = 0.f;
#pragma unroll
        for (int i = 0; i < 16; i++) d += rv[i] * qr[i];
        d = wsum(d);
        float p = __expf(fminf(d, 60.f));   // scores O(1): max-free softmax
        ssum += p;
#pragma unroll
        for (int i = 0; i < 16; i++) cacc[i] += p * rv[i];
    }

#pragma unroll
    for (int i = 0; i < 16; i++) scacc[wid][lane * 17 + i] = cacc[i];
    if (lane == 0) sS[n][lh] = ssum;
    // shb: 512 threads load 1024 elements
    shb[tid]       = __bfloat162float(hcur[(size_t)b * 1024 + tid]);
    shb[tid + 512] = __bfloat162float(hcur[(size_t)b * 1024 + tid + 512]);
    __syncthreads();

    // merge 2 l-halves per n (plain sums), normalize (1/16), max-pool over n
#pragma unroll
    for (int pass = 0; pass < 2; pass++) {
        int e = tid + pass * 512;
        int eo = (e >> 4) * 17 + (e & 15);
        float pool = -1e30f;
#pragma unroll
        for (int nn = 0; nn < 4; nn++) {
            float S = sS[nn][0] + sS[nn][1];
            float V = scacc[nn * 2 + 0][eo] + scacc[nn * 2 + 1][eo];
            pool = fmaxf(pool, V / (16.0f * S));
        }
        spool[e] = pool;
    }
    __syncthreads();

    // logits: wave wid computes prods wid*8 .. wid*8+7
#pragma unroll
    for (int pi = 0; pi < 8; pi++) {
        int p = wid * 8 + pi;
        const __hip_bfloat16* wr = WcT + (size_t)p * 2048;
        float s = 0.f;
#pragma unroll
        for (int jj = 0; jj < 16; jj++) {
            int e = lane + jj * 64;
            s += shb[e] * __bfloat162float(wr[e]);
            s += spool[e] * __bfloat162float(wr[1024 + e]);
        }
        s = wsum(s);
        if (lane == 0) slg[p] = s + bcomp[p];
    }
    __syncthreads();
    if (tid < 64) {
        float v = slg[tid];
        float m2 = wmaxr(v);
        float se = wsum(__expf(v - m2));
        int a = actions[b * 32 + t];
        if (tid == a) nll[b] -= (v - m2 - __logf(se));
    }
}

// ---------------- decoder init: max-pool final states over io examples -------
__global__ __launch_bounds__(256) void kinit_dec(
    const __hip_bfloat16* __restrict__ hf,  // final h (buf0): [2][1024][512]
    const float* __restrict__ cf,
    __hip_bfloat16* __restrict__ h0,        // [256][1024]
    float* __restrict__ c0)
{
    int idx = blockIdx.x * 256 + threadIdx.x;
    int b = idx >> 10, e = idx & 1023;
    int dir = e >> 9, u = e & 511;
    const __hip_bfloat16* hs = hf + (size_t)dir * 1024 * 512;
    const float* cs = cf + (size_t)dir * 1024 * 512;
    float hv = -3.4e38f, cv = -3.4e38f;
#pragma unroll
    for (int n = 0; n < 4; n++) {
        size_t ix = (size_t)(b * 4 + n) * 512 + u;
        hv = fmaxf(hv, __bfloat162float(hs[ix]));
        cv = fmaxf(cv, cs[ix]);
    }
    h0[idx] = __float2bfloat16(hv);
    c0[idx] = cv;
}

__global__ void kfinal(const float* __restrict__ nll, void* __restrict__ out,
                       const int* __restrict__ mode) {
    int i = threadIdx.x;
    if (*mode) ((__hip_bfloat16*)out)[i] = __float2bfloat16(nll[i]);
    else       ((float*)out)[i] = nll[i];
}

// -----------------------------------------------------------------------------
extern "C" void kernel_launch(void* const* d_in, const int* in_sizes, int n_in,
                              void* d_out, int out_size, void* d_ws, size_t ws_size,
                              hipStream_t stream) {
    const int* exs = (const int*)d_in[0];
    const int* cls = (const int*)d_in[1];
    const void* E_raw     = d_in[2];
    const void* WiF_raw   = d_in[3];
    const void* WhF_raw   = d_in[4];
    const void* bF_raw    = d_in[5];
    const void* WiB_raw   = d_in[6];
    const void* WhB_raw   = d_in[7];
    const void* bB_raw    = d_in[8];
    const void* Wattn_raw = d_in[9];
    const void* Wcomp_raw = d_in[10];
    const void* bcomp_raw = d_in[11];
    const void* vWi_raw   = d_in[12];
    const void* vWh_raw   = d_in[13];
    const void* vb_raw    = d_in[14];
    const void* fe_raw    = d_in[15];
    const int* actions = (const int*)d_in[16];
    (void)in_sizes; (void)n_in; (void)out_size; (void)ws_size;

    char* w = (char*)d_ws;
    size_t off = 0;
    auto take = [&](size_t bytes) -> char* {
        char* p = w + off;
        off = (off + bytes + 255) & ~(size_t)255;
        return p;
    };
    __hip_bfloat16* WhT    = (__hip_bfloat16*)take(2ull * 2048 * 512 * 2);
    __hip_bfloat16* WiT    = (__hip_bfloat16*)take(2ull * 2048 * 256 * 2);
    __hip_bfloat16* vWhT   = (__hip_bfloat16*)take(4096ull * 1024 * 2);
    __hip_bfloat16* vWiT   = (__hip_bfloat16*)take(4096ull * 1024 * 2);
    __hip_bfloat16* WattnT = (__hip_bfloat16*)take(1024ull * 1024 * 2);
    __hip_bfloat16* WcT    = (__hip_bfloat16*)take(64ull * 2048 * 2);
    __hip_bfloat16* Ebf    = (__hip_bfloat16*)take(128ull * 128 * 2);
    __hip_bfloat16* febf   = (__hip_bfloat16*)take(32ull * 1024 * 2);
    float* bFf   = (float*)take(2048 * 4);
    float* bBf   = (float*)take(2048 * 4);
    float* bcf   = (float*)take(64 * 4);
    float* vbf   = (float*)take(4096 * 4);
    float* Gtab  = (float*)take(4ull * 128 * 2048 * 4);
    float* VX    = (float*)take(32ull * 4096 * 4);
    __hip_bfloat16* hEnc = (__hip_bfloat16*)take(2ull * 2 * 1024 * 512 * 2); // [buf][dir][1024][512]
    float* cEnc = (float*)take(2ull * 1024 * 512 * 4);
    __hip_bfloat16* hDec = (__hip_bfloat16*)take(2ull * 256 * 1024 * 2);
    float* cDec = (float*)take(256ull * 1024 * 4);
    float* qbuf = (float*)take(256ull * 1024 * 4);
    float* nll  = (float*)take(256 * 4);
    int*   mode = (int*)take(256);
    unsigned char* ctx8 = (unsigned char*)take(64ull * 1024 * 1024);  // fp8 [64][256][4][1024]

    (void)hipMemsetAsync(hEnc, 0, 2ull * 1024 * 512 * 2, stream);  // h buf0, both dirs
    (void)hipMemsetAsync(cEnc, 0, 2ull * 1024 * 512 * 4, stream);
    (void)hipMemsetAsync(nll, 0, 256 * 4, stream);

    kdetect<<<1, 128, 0, stream>>>((const unsigned int*)E_raw, mode);

    kcvt_bf16<<<64, 256, 0, stream>>>(E_raw,  Ebf,  128 * 128, mode);
    kcvt_bf16<<<128, 256, 0, stream>>>(fe_raw, febf, 32 * 1024, mode);
    kcvt_f32<<<8, 256, 0, stream>>>(bF_raw, bFf, 2048, mode);
    kcvt_f32<<<8, 256, 0, stream>>>(bB_raw, bBf, 2048, mode);
    kcvt_f32<<<1, 256, 0, stream>>>(bcomp_raw, bcf, 64, mode);
    kcvt_f32<<<16, 256, 0, stream>>>(vb_raw, vbf, 4096, mode);

    ktranspose_cvt<<<dim3(32, 8),  256, 0, stream>>>(WhF_raw,   WhT,              512, 2048, mode);
    ktranspose_cvt<<<dim3(32, 8),  256, 0, stream>>>(WhB_raw,   WhT + 2048 * 512, 512, 2048, mode);
    ktranspose_cvt<<<dim3(32, 4),  256, 0, stream>>>(WiF_raw,   WiT,              256, 2048, mode);
    ktranspose_cvt<<<dim3(32, 4),  256, 0, stream>>>(WiB_raw,   WiT + 2048 * 256, 256, 2048, mode);
    ktranspose_cvt<<<dim3(64, 16), 256, 0, stream>>>(vWh_raw,   vWhT,            1024, 4096, mode);
    ktranspose_cvt<<<dim3(64, 16), 256, 0, stream>>>(vWi_raw,   vWiT,            1024, 4096, mode);
    ktranspose_cvt<<<dim3(16, 16), 256, 0, stream>>>(Wattn_raw, WattnT,          1024, 1024, mode);
    ktranspose_cvt<<<dim3(1, 32),  256, 0, stream>>>(Wcomp_raw, WcT,             2048, 64,   mode);

    kprep_gtab<<<256, 256, 0, stream>>>(Ebf, WiT, bFf, bBf, Gtab);
    kprep_vx<<<32, 256, 0, stream>>>(febf, vWiT, vbf, VX);

    const size_t HB = 2ull * 1024 * 512;
    for (int t = 0; t < 64; t++) {
        kenc_step<<<512, 256, 0, stream>>>(t, WhT, Gtab, exs, cls,
                                           hEnc + (size_t)(t & 1) * HB,
                                           hEnc + (size_t)((t + 1) & 1) * HB,
                                           cEnc, ctx8);
    }
    kinit_dec<<<1024, 256, 0, stream>>>(hEnc, cEnc, hDec, cDec);

    const size_t HD = 256ull * 1024;
    for (int t = 0; t < 32; t++) {
        const __hip_bfloat16* hcur = hDec + (size_t)(t & 1) * HD;
        kdec_gemm<<<256, 256, 0, stream>>>(t, vWhT, WattnT, VX, hcur,
                                           hDec + (size_t)((t + 1) & 1) * HD, cDec, qbuf);
        kattn<<<256, 512, 0, stream>>>(t, qbuf, ctx8, hcur, WcT, bcf, actions, nll);
    }
    kfinal<<<1, 256, 0, stream>>>(nll, d_out, mode);
}

// Round 8
// 2349.122 us; speedup vs baseline: 2.7396x; 1.2839x over previous
//
#include <hip/hip_runtime.h>
#include <hip/hip_bf16.h>

typedef __bf16 bf16x8 __attribute__((ext_vector_type(8)));
typedef float  f32x4  __attribute__((ext_vector_type(4)));
typedef float  f32x2  __attribute__((ext_vector_type(2)));
typedef unsigned int u32x4 __attribute__((ext_vector_type(4)));
typedef unsigned short ushort_t;
static_assert(sizeof(bf16x8) == 16, "bf16x8 must be 16B");

#define DEV __device__ __forceinline__

DEV f32x4 mfma16(bf16x8 a, bf16x8 b, f32x4 c) {
    return __builtin_amdgcn_mfma_f32_16x16x32_bf16(a, b, c, 0, 0, 0);
}
DEV float wsum(float v) {
#pragma unroll
    for (int o = 32; o > 0; o >>= 1) v += __shfl_xor(v, o, 64);
    return v;
}
DEV float wmaxr(float v) {
#pragma unroll
    for (int o = 32; o > 0; o >>= 1) v = fmaxf(v, __shfl_xor(v, o, 64));
    return v;
}
DEV float sigm(float x)   { return 1.0f / (1.0f + __expf(-x)); }
DEV float tanh_f(float x) { return 2.0f / (1.0f + __expf(-2.0f * x)) - 1.0f; }

// async global->LDS, 16B per lane; lds dest must be wave-uniform base (+lane*16)
DEV void glds16(const __hip_bfloat16* g, __hip_bfloat16* l) {
    __builtin_amdgcn_global_load_lds(
        (const __attribute__((address_space(1))) unsigned int*)g,
        (__attribute__((address_space(3))) unsigned int*)l, 16, 0, 0);
}

DEV unsigned char f32_to_fp8(float v) {
    int p = __builtin_amdgcn_cvt_pk_fp8_f32(v, v, 0, false);
    return (unsigned char)(p & 0xFF);
}
DEV void fp8x4_to_f32(unsigned int w, float* out) {
    f32x2 lo = __builtin_amdgcn_cvt_pk_f32_fp8(w, false);
    f32x2 hi = __builtin_amdgcn_cvt_pk_f32_fp8(w, true);
    out[0] = lo[0]; out[1] = lo[1]; out[2] = hi[0]; out[3] = hi[1];
}

// ---------------- dtype detection: 1 = inputs are bf16, 0 = inputs are fp32 --
__global__ __launch_bounds__(128) void kdetect(const unsigned int* __restrict__ raw,
                                               int* __restrict__ mode) {
    __shared__ int cnt;
    if (threadIdx.x == 0) cnt = 0;
    __syncthreads();
    unsigned int w = raw[threadIdx.x];
    unsigned short lo = (unsigned short)(w & 0xFFFFu);
    unsigned int f32bits = ((unsigned int)lo) << 16;
    float v;
    __builtin_memcpy(&v, &f32bits, 4);
    float a = fabsf(v);
    if (a >= 1e-4f && a <= 1.0f) atomicAdd(&cnt, 1);
    __syncthreads();
    if (threadIdx.x == 0) *mode = (cnt >= 64) ? 1 : 0;
}

__global__ __launch_bounds__(256) void kcvt_bf16(const void* __restrict__ src,
                                                 __hip_bfloat16* __restrict__ dst,
                                                 int n, const int* __restrict__ mode) {
    int i = blockIdx.x * 256 + threadIdx.x;
    if (i >= n) return;
    if (*mode) dst[i] = ((const __hip_bfloat16*)src)[i];
    else       dst[i] = __float2bfloat16(((const float*)src)[i]);
}

__global__ __launch_bounds__(256) void kcvt_f32(const void* __restrict__ src,
                                                float* __restrict__ dst,
                                                int n, const int* __restrict__ mode) {
    int i = blockIdx.x * 256 + threadIdx.x;
    if (i >= n) return;
    if (*mode) dst[i] = __bfloat162float(((const __hip_bfloat16*)src)[i]);
    else       dst[i] = ((const float*)src)[i];
}

// --------- tiled transpose + convert: out_bf16[c][r] = (bf16)in[r][c] --------
__global__ __launch_bounds__(256) void ktranspose_cvt(const void* __restrict__ src,
                                                      __hip_bfloat16* __restrict__ out,
                                                      int R, int C,
                                                      const int* __restrict__ mode) {
    __shared__ float tile[64][65];
    int c0 = blockIdx.x * 64, r0 = blockIdx.y * 64;
    int tx = threadIdx.x & 63, ty = threadIdx.x >> 6;
    int m = *mode;
#pragma unroll
    for (int i = ty; i < 64; i += 4) {
        size_t ix = (size_t)(r0 + i) * C + (c0 + tx);
        tile[i][tx] = m ? __bfloat162float(((const __hip_bfloat16*)src)[ix])
                        : ((const float*)src)[ix];
    }
    __syncthreads();
#pragma unroll
    for (int i = ty; i < 64; i += 4)
        out[(size_t)(c0 + i) * R + (r0 + tx)] = __float2bfloat16(tile[tx][i]);
}

// ------ prep: G tables, gate-interleaved: G[dh][v][u<512][g<4] = E@Wi (+b) ---
__global__ __launch_bounds__(256) void kprep_gtab(
    const __hip_bfloat16* __restrict__ E,    // [128][128]
    const __hip_bfloat16* __restrict__ WiT,  // [2][2048][256]
    const float* __restrict__ bF,
    const float* __restrict__ bB,
    float* __restrict__ G)                   // [4][128][512][4]
{
    int dh = blockIdx.x >> 6;
    int dir = dh >> 1, half = dh & 1;
    int m0 = ((blockIdx.x >> 5) & 1) * 64;
    int n0 = (blockIdx.x & 31) * 64;
    int lane = threadIdx.x & 63, wid = threadIdx.x >> 6;
    int wrow = wid >> 1, wcol = wid & 1;
    int r16 = lane & 15, quad = lane >> 4;

    f32x4 acc[2][2] = {};
    const __hip_bfloat16* Ap = E + (size_t)(m0 + wrow * 32 + r16) * 128 + quad * 8;
    const __hip_bfloat16* Bp = WiT + (size_t)dir * 2048 * 256
                             + (size_t)(n0 + wcol * 32 + r16) * 256 + half * 128 + quad * 8;
#pragma unroll
    for (int kb = 0; kb < 128; kb += 32) {
        bf16x8 a0 = *(const bf16x8*)(Ap + kb);
        bf16x8 a1 = *(const bf16x8*)(Ap + 16 * 128 + kb);
        bf16x8 b0 = *(const bf16x8*)(Bp + kb);
        bf16x8 b1 = *(const bf16x8*)(Bp + 16 * 256 + kb);
        acc[0][0] = mfma16(a0, b0, acc[0][0]);
        acc[0][1] = mfma16(a0, b1, acc[0][1]);
        acc[1][0] = mfma16(a1, b0, acc[1][0]);
        acc[1][1] = mfma16(a1, b1, acc[1][1]);
    }
    const float* bias = dir ? bB : bF;
    float* Gt = G + (size_t)dh * 128 * 2048;
#pragma unroll
    for (int rt = 0; rt < 2; rt++)
#pragma unroll
        for (int ct = 0; ct < 2; ct++)
#pragma unroll
            for (int r = 0; r < 4; r++) {
                int mm = m0 + wrow * 32 + rt * 16 + quad * 4 + r;
                int j = n0 + wcol * 32 + ct * 16 + r16;
                float v = acc[rt][ct][r];
                if (half == 0) v += bias[j];
                int g = j >> 9, u = j & 511;
                Gt[((size_t)mm * 512 + u) * 4 + g] = v;
            }
}

// ---------------- prep: VX[t][j] = field_emb @ v_Wi + v_b --------------------
__global__ __launch_bounds__(256) void kprep_vx(
    const __hip_bfloat16* __restrict__ fe,    // [32][1024]
    const __hip_bfloat16* __restrict__ vWiT,  // [4096][1024]
    const float* __restrict__ vb,             // [4096]
    float* __restrict__ VX)                   // [32][4096]
{
    int n0 = blockIdx.x * 128;
    int lane = threadIdx.x & 63, wid = threadIdx.x >> 6;
    int r16 = lane & 15, quad = lane >> 4;
    f32x4 acc[2][2] = {};
    const __hip_bfloat16* Ap = fe + (size_t)r16 * 1024 + quad * 8;
    const __hip_bfloat16* Bp = vWiT + (size_t)(n0 + wid * 32 + r16) * 1024 + quad * 8;
    for (int kb = 0; kb < 1024; kb += 32) {
        bf16x8 a0 = *(const bf16x8*)(Ap + kb);
        bf16x8 a1 = *(const bf16x8*)(Ap + 16 * 1024 + kb);
        bf16x8 b0 = *(const bf16x8*)(Bp + kb);
        bf16x8 b1 = *(const bf16x8*)(Bp + 16 * 1024 + kb);
        acc[0][0] = mfma16(a0, b0, acc[0][0]);
        acc[0][1] = mfma16(a0, b1, acc[0][1]);
        acc[1][0] = mfma16(a1, b0, acc[1][0]);
        acc[1][1] = mfma16(a1, b1, acc[1][1]);
    }
#pragma unroll
    for (int rt = 0; rt < 2; rt++)
#pragma unroll
        for (int ct = 0; ct < 2; ct++)
#pragma unroll
            for (int r = 0; r < 4; r++) {
                int m = rt * 16 + quad * 4 + r;
                int j = n0 + wid * 32 + ct * 16 + r16;
                VX[(size_t)m * 4096 + j] = acc[rt][ct][r] + vb[j];
            }
}

// ======== encoder LSTM step: 512 blocks (dir x 32 mt x 8 us), 32m x 64u ======
__global__ __launch_bounds__(256, 2) void kenc_step(
    int t,
    const __hip_bfloat16* __restrict__ WhT,   // [2][2048][512]
    const float* __restrict__ Gtab,           // [4][128][512][4]
    const int* __restrict__ exs,
    const int* __restrict__ cls,
    const __hip_bfloat16* __restrict__ h_in,  // [2][1024][512]
    __hip_bfloat16* __restrict__ h_out,
    float* __restrict__ c_st,                 // [2][1024][512]
    unsigned char* __restrict__ ctx8)         // [64][256][4][1024] fp8 (x16)
{
    __shared__ __align__(16) __hip_bfloat16 sA[2][32 * 64];
    __shared__ __align__(16) __hip_bfloat16 sB[2][256 * 64];

    int bid = blockIdx.x;
    int dir = bid >> 8;
    int mt  = (bid >> 3) & 31;
    int us  = bid & 7;
    int l = dir ? (63 - t) : t;
    int m0 = mt * 32, u0 = us * 64;

    int lane = threadIdx.x & 63, w = threadIdx.x >> 6;
    int r16 = lane & 15, quad = lane >> 4;
    int srow = lane >> 3, scol = (lane & 7) * 8;   // 8 rows per glds16 call

    const __hip_bfloat16* Ab = h_in + (size_t)dir * 1024 * 512;
    const __hip_bfloat16* Bb = WhT + (size_t)dir * 2048 * 512;

    f32x4 acc[4][2] = {};  // [gate][mi]

    auto stage = [&](int buf, int it) {
        int kb = it * 64;
        glds16(Ab + (size_t)(m0 + w * 8 + srow) * 512 + kb + scol,
               &sA[buf][(w * 8) * 64]);
#pragma unroll
        for (int c = 0; c < 8; c++) {
            int rl = w * 64 + c * 8;
            int rr = rl + srow;
            int g = rr >> 6, j = rr & 63;
            glds16(Bb + (size_t)(g * 512 + u0 + j) * 512 + kb + scol,
                   &sB[buf][rl * 64]);
        }
    };

    stage(0, 0);
    __syncthreads();
    int buf = 0;
    const int NIT = 8;  // 512/64
    for (int it = 0; it < NIT; it++) {
        if (it + 1 < NIT) stage(buf ^ 1, it + 1);
#pragma unroll
        for (int k32 = 0; k32 < 64; k32 += 32) {
            bf16x8 a[2], bf[4];
#pragma unroll
            for (int mi = 0; mi < 2; mi++)
                a[mi] = *(const bf16x8*)&sA[buf][(mi * 16 + r16) * 64 + k32 + quad * 8];
#pragma unroll
            for (int g = 0; g < 4; g++)
                bf[g] = *(const bf16x8*)&sB[buf][(g * 64 + w * 16 + r16) * 64 + k32 + quad * 8];
#pragma unroll
            for (int g = 0; g < 4; g++)
#pragma unroll
                for (int mi = 0; mi < 2; mi++)
                    acc[g][mi] = mfma16(a[mi], bf[g], acc[g][mi]);
        }
        __syncthreads();
        buf ^= 1;
    }

    // epilogue: thread owns u = u0 + w*16 + r16, 8 m's
    int u = u0 + w * 16 + r16;
    size_t cbase = (size_t)dir * 1024 * 512;
    const float* GeT = Gtab + (size_t)(dir * 2) * 128 * 2048;
    const float* GcT = GeT + 128 * 2048;
#pragma unroll
    for (int mi = 0; mi < 2; mi++)
#pragma unroll
        for (int r = 0; r < 4; r++) {
            int m = m0 + mi * 16 + quad * 4 + r;
            int vE = exs[l * 1024 + m], vC = cls[l * 1024 + m];
            f32x4 ge = *(const f32x4*)&GeT[((size_t)vE * 512 + u) * 4];
            f32x4 gc = *(const f32x4*)&GcT[((size_t)vC * 512 + u) * 4];
            float gi = acc[0][mi][r] + ge[0] + gc[0];
            float gf = acc[1][mi][r] + ge[1] + gc[1];
            float gg = acc[2][mi][r] + ge[2] + gc[2];
            float go = acc[3][mi][r] + ge[3] + gc[3];
            size_t cix = cbase + (size_t)m * 512 + u;
            float cn = sigm(gf) * c_st[cix] + sigm(gi) * tanh_f(gg);
            c_st[cix] = cn;
            float hn = sigm(go) * tanh_f(cn);
            h_out[cix] = __float2bfloat16(hn);
            ctx8[(((size_t)l * 256 + (m >> 2)) * 4 + (m & 3)) * 1024 + dir * 512 + u]
                = f32_to_fp8(hn * 16.0f);
        }
}

// ======== decoder fused GEMM: cell (0..127: 32m x 64u) + q (128..255) ========
__global__ __launch_bounds__(256, 2) void kdec_gemm(
    int t,
    const __hip_bfloat16* __restrict__ vWhT,   // [4096][1024]
    const __hip_bfloat16* __restrict__ WattnT, // [1024][1024]
    const float* __restrict__ VX,              // [32][4096]
    const __hip_bfloat16* __restrict__ h_in,   // [256][1024]  (h_t = hAll[t])
    __hip_bfloat16* __restrict__ h_out,        // [256][1024]  (hAll[t+1])
    float* __restrict__ c_st,                  // [256][1024]
    float* __restrict__ qout)                  // [256][1024]  (qall[t])
{
    __shared__ __align__(16) __hip_bfloat16 sA[2][32 * 64];
    __shared__ __align__(16) __hip_bfloat16 sB[2][256 * 64];

    int bid = blockIdx.x;
    int lane = threadIdx.x & 63, w = threadIdx.x >> 6;
    int r16 = lane & 15, quad = lane >> 4;
    int srow = lane >> 3, scol = (lane & 7) * 8;
    const int NIT = 16;  // 1024/64

    if (bid < 128) {
        int m0 = (bid >> 4) * 32, u0 = (bid & 15) * 64;
        f32x4 acc[4][2] = {};
        auto stage = [&](int buf, int it) {
            int kb = it * 64;
            glds16(h_in + (size_t)(m0 + w * 8 + srow) * 1024 + kb + scol,
                   &sA[buf][(w * 8) * 64]);
#pragma unroll
            for (int c = 0; c < 8; c++) {
                int rl = w * 64 + c * 8;
                int rr = rl + srow;
                int g = rr >> 6, j = rr & 63;
                glds16(vWhT + (size_t)(g * 1024 + u0 + j) * 1024 + kb + scol,
                       &sB[buf][rl * 64]);
            }
        };
        stage(0, 0);
        __syncthreads();
        int buf = 0;
        for (int it = 0; it < NIT; it++) {
            if (it + 1 < NIT) stage(buf ^ 1, it + 1);
#pragma unroll
            for (int k32 = 0; k32 < 64; k32 += 32) {
                bf16x8 a[2], bf[4];
#pragma unroll
                for (int mi = 0; mi < 2; mi++)
                    a[mi] = *(const bf16x8*)&sA[buf][(mi * 16 + r16) * 64 + k32 + quad * 8];
#pragma unroll
                for (int g = 0; g < 4; g++)
                    bf[g] = *(const bf16x8*)&sB[buf][(g * 64 + w * 16 + r16) * 64 + k32 + quad * 8];
#pragma unroll
                for (int g = 0; g < 4; g++)
#pragma unroll
                    for (int mi = 0; mi < 2; mi++)
                        acc[g][mi] = mfma16(a[mi], bf[g], acc[g][mi]);
            }
            __syncthreads();
            buf ^= 1;
        }
        int u = u0 + w * 16 + r16;
        const float* vx = VX + (size_t)t * 4096;
        float v0 = vx[u], v1 = vx[1024 + u], v2 = vx[2048 + u], v3 = vx[3072 + u];
#pragma unroll
        for (int mi = 0; mi < 2; mi++)
#pragma unroll
            for (int r = 0; r < 4; r++) {
                int m = m0 + mi * 16 + quad * 4 + r;
                float gi = acc[0][mi][r] + v0;
                float gf = acc[1][mi][r] + v1;
                float gg = acc[2][mi][r] + v2;
                float go = acc[3][mi][r] + v3;
                size_t cix = (size_t)m * 1024 + u;
                float cn = sigm(gf) * c_st[cix] + sigm(gi) * tanh_f(gg);
                c_st[cix] = cn;
                h_out[cix] = __float2bfloat16(sigm(go) * tanh_f(cn));
            }
    } else {
        int b2 = bid - 128;
        int m0 = (b2 >> 4) * 32, n0 = (b2 & 15) * 64;
        f32x4 acc[2] = {};
        auto stage = [&](int buf, int it) {
            int kb = it * 64;
            glds16(h_in + (size_t)(m0 + w * 8 + srow) * 1024 + kb + scol,
                   &sA[buf][(w * 8) * 64]);
#pragma unroll
            for (int c = 0; c < 2; c++) {
                int rl = w * 16 + c * 8;
                glds16(WattnT + (size_t)(n0 + rl + srow) * 1024 + kb + scol,
                       &sB[buf][rl * 64]);
            }
        };
        stage(0, 0);
        __syncthreads();
        int buf = 0;
        for (int it = 0; it < NIT; it++) {
            if (it + 1 < NIT) stage(buf ^ 1, it + 1);
#pragma unroll
            for (int k32 = 0; k32 < 64; k32 += 32) {
                bf16x8 a[2];
#pragma unroll
                for (int mi = 0; mi < 2; mi++)
                    a[mi] = *(const bf16x8*)&sA[buf][(mi * 16 + r16) * 64 + k32 + quad * 8];
                bf16x8 bf = *(const bf16x8*)&sB[buf][(w * 16 + r16) * 64 + k32 + quad * 8];
#pragma unroll
                for (int mi = 0; mi < 2; mi++)
                    acc[mi] = mfma16(a[mi], bf, acc[mi]);
            }
            __syncthreads();
            buf ^= 1;
        }
        int n = n0 + w * 16 + r16;
#pragma unroll
        for (int mi = 0; mi < 2; mi++)
#pragma unroll
            for (int r = 0; r < 4; r++) {
                int m = m0 + mi * 16 + quad * 4 + r;
                qout[(size_t)m * 1024 + n] = acc[mi][r];
            }
    }
}

// ======== batched attention over ALL (b, t): grid (256, 32), 512 threads =====
// kattn(t) does not feed the recurrence -> run all 32 t in one dispatch.
__global__ __launch_bounds__(512, 2) void kattn_all(
    const float* __restrict__ qall,           // [32][256][1024]
    const unsigned char* __restrict__ ctx8,   // [64][256][4][1024] fp8 (x16)
    const __hip_bfloat16* __restrict__ hAll,  // [33][256][1024]
    const __hip_bfloat16* __restrict__ WcT,   // [64][2048]
    const float* __restrict__ bcomp,          // [64]
    const int* __restrict__ actions,          // [256][32]
    float* __restrict__ nllT)                 // [32][256]
{
    __shared__ float scacc[8][64 * 17];       // stride-17, [wid][element]
    __shared__ float sS[4][2];
    __shared__ float spool[1024];
    __shared__ float shb[1024];
    __shared__ float slg[64];

    int b = blockIdx.x;
    int t = blockIdx.y;
    int tid = threadIdx.x;
    int lane = tid & 63, wid = tid >> 6;      // 8 waves
    int n = wid >> 1, lh = wid & 1;           // io-example n, l-half lh

    float qr[16];
    {
        const float* qp = qall + ((size_t)t * 256 + b) * 1024 + lane * 16;
#pragma unroll
        for (int i = 0; i < 16; i++) qr[i] = qp[i] * 0.0625f;  // fold 1/16 fp8 scale
    }

    const size_t LSTR = 1024 * 1024;          // ctx8 l-stride bytes
    const unsigned char* cb = ctx8 + ((size_t)b * 4 + n) * 1024 + lane * 16
                            + (size_t)(lh * 32) * LSTR;

    float ssum = 0.f;
    float cacc[16];
#pragma unroll
    for (int i = 0; i < 16; i++) cacc[i] = 0.f;

    u32x4 rw[4];
#pragma unroll
    for (int j = 0; j < 4; j++)
        rw[j] = *(const u32x4*)(cb + (size_t)j * LSTR);

    for (int j = 0; j < 32; j++) {
        u32x4 wv = rw[j & 3];
        if (j + 4 < 32)
            rw[j & 3] = *(const u32x4*)(cb + (size_t)(j + 4) * LSTR);
        float rv[16];
        fp8x4_to_f32(wv[0], rv);
        fp8x4_to_f32(wv[1], rv + 4);
        fp8x4_to_f32(wv[2], rv + 8);
        fp8x4_to_f32(wv[3], rv + 12);
        float d = 0.f;
#pragma unroll
        for (int i = 0; i < 16; i++) d += rv[i] * qr[i];
        d = wsum(d);
        float p = __expf(fminf(d, 60.f));   // scores O(1): max-free softmax
        ssum += p;
#pragma unroll
        for (int i = 0; i < 16; i++) cacc[i] += p * rv[i];
    }

#pragma unroll
    for (int i = 0; i < 16; i++) scacc[wid][lane * 17 + i] = cacc[i];
    if (lane == 0) sS[n][lh] = ssum;
    const __hip_bfloat16* hcur = hAll + ((size_t)t * 256 + b) * 1024;
    shb[tid]       = __bfloat162float(hcur[tid]);
    shb[tid + 512] = __bfloat162float(hcur[tid + 512]);
    __syncthreads();

    // merge 2 l-halves per n (plain sums), normalize (1/16), max-pool over n
#pragma unroll
    for (int pass = 0; pass < 2; pass++) {
        int e = tid + pass * 512;
        int eo = (e >> 4) * 17 + (e & 15);
        float pool = -1e30f;
#pragma unroll
        for (int nn = 0; nn < 4; nn++) {
            float S = sS[nn][0] + sS[nn][1];
            float V = scacc[nn * 2 + 0][eo] + scacc[nn * 2 + 1][eo];
            pool = fmaxf(pool, V / (16.0f * S));
        }
        spool[e] = pool;
    }
    __syncthreads();

    // logits: wave wid computes prods wid*8 .. wid*8+7
#pragma unroll
    for (int pi = 0; pi < 8; pi++) {
        int p = wid * 8 + pi;
        const __hip_bfloat16* wr = WcT + (size_t)p * 2048;
        float s = 0.f;
#pragma unroll
        for (int jj = 0; jj < 16; jj++) {
            int e = lane + jj * 64;
            s += shb[e] * __bfloat162float(wr[e]);
            s += spool[e] * __bfloat162float(wr[1024 + e]);
        }
        s = wsum(s);
        if (lane == 0) slg[p] = s + bcomp[p];
    }
    __syncthreads();
    if (tid < 64) {
        float v = slg[tid];
        float m2 = wmaxr(v);
        float se = wsum(__expf(v - m2));
        int a = actions[b * 32 + t];
        if (tid == a) nllT[t * 256 + b] = m2 + __logf(se) - v;
    }
}

// ---------------- decoder init: max-pool final states over io examples -------
__global__ __launch_bounds__(256) void kinit_dec(
    const __hip_bfloat16* __restrict__ hf,  // final h (buf0): [2][1024][512]
    const float* __restrict__ cf,
    __hip_bfloat16* __restrict__ h0,        // [256][1024] (hAll[0])
    float* __restrict__ c0)
{
    int idx = blockIdx.x * 256 + threadIdx.x;
    int b = idx >> 10, e = idx & 1023;
    int dir = e >> 9, u = e & 511;
    const __hip_bfloat16* hs = hf + (size_t)dir * 1024 * 512;
    const float* cs = cf + (size_t)dir * 1024 * 512;
    float hv = -3.4e38f, cv = -3.4e38f;
#pragma unroll
    for (int n = 0; n < 4; n++) {
        size_t ix = (size_t)(b * 4 + n) * 512 + u;
        hv = fmaxf(hv, __bfloat162float(hs[ix]));
        cv = fmaxf(cv, cs[ix]);
    }
    h0[idx] = __float2bfloat16(hv);
    c0[idx] = cv;
}

__global__ void kfinal(const float* __restrict__ nllT, void* __restrict__ out,
                       const int* __restrict__ mode) {
    int i = threadIdx.x;
    float s = 0.f;
#pragma unroll
    for (int t = 0; t < 32; t++) s += nllT[t * 256 + i];
    if (*mode) ((__hip_bfloat16*)out)[i] = __float2bfloat16(s);
    else       ((float*)out)[i] = s;
}

// -----------------------------------------------------------------------------
extern "C" void kernel_launch(void* const* d_in, const int* in_sizes, int n_in,
                              void* d_out, int out_size, void* d_ws, size_t ws_size,
                              hipStream_t stream) {
    const int* exs = (const int*)d_in[0];
    const int* cls = (const int*)d_in[1];
    const void* E_raw     = d_in[2];
    const void* WiF_raw   = d_in[3];
    const void* WhF_raw   = d_in[4];
    const void* bF_raw    = d_in[5];
    const void* WiB_raw   = d_in[6];
    const void* WhB_raw   = d_in[7];
    const void* bB_raw    = d_in[8];
    const void* Wattn_raw = d_in[9];
    const void* Wcomp_raw = d_in[10];
    const void* bcomp_raw = d_in[11];
    const void* vWi_raw   = d_in[12];
    const void* vWh_raw   = d_in[13];
    const void* vb_raw    = d_in[14];
    const void* fe_raw    = d_in[15];
    const int* actions = (const int*)d_in[16];
    (void)in_sizes; (void)n_in; (void)out_size; (void)ws_size;

    char* w = (char*)d_ws;
    size_t off = 0;
    auto take = [&](size_t bytes) -> char* {
        char* p = w + off;
        off = (off + bytes + 255) & ~(size_t)255;
        return p;
    };
    __hip_bfloat16* WhT    = (__hip_bfloat16*)take(2ull * 2048 * 512 * 2);
    __hip_bfloat16* WiT    = (__hip_bfloat16*)take(2ull * 2048 * 256 * 2);
    __hip_bfloat16* vWhT   = (__hip_bfloat16*)take(4096ull * 1024 * 2);
    __hip_bfloat16* vWiT   = (__hip_bfloat16*)take(4096ull * 1024 * 2);
    __hip_bfloat16* WattnT = (__hip_bfloat16*)take(1024ull * 1024 * 2);
    __hip_bfloat16* WcT    = (__hip_bfloat16*)take(64ull * 2048 * 2);
    __hip_bfloat16* Ebf    = (__hip_bfloat16*)take(128ull * 128 * 2);
    __hip_bfloat16* febf   = (__hip_bfloat16*)take(32ull * 1024 * 2);
    float* bFf   = (float*)take(2048 * 4);
    float* bBf   = (float*)take(2048 * 4);
    float* bcf   = (float*)take(64 * 4);
    float* vbf   = (float*)take(4096 * 4);
    float* Gtab  = (float*)take(4ull * 128 * 2048 * 4);
    float* VX    = (float*)take(32ull * 4096 * 4);
    __hip_bfloat16* hEnc = (__hip_bfloat16*)take(2ull * 2 * 1024 * 512 * 2); // [buf][dir][1024][512]
    float* cEnc = (float*)take(2ull * 1024 * 512 * 4);
    __hip_bfloat16* hAll = (__hip_bfloat16*)take(33ull * 256 * 1024 * 2);    // h_0..h_32
    float* cDec = (float*)take(256ull * 1024 * 4);
    float* qall = (float*)take(32ull * 256 * 1024 * 4);
    float* nllT = (float*)take(32ull * 256 * 4);
    int*   mode = (int*)take(256);
    unsigned char* ctx8 = (unsigned char*)take(64ull * 1024 * 1024);  // fp8 [64][256][4][1024]

    (void)hipMemsetAsync(hEnc, 0, 2ull * 1024 * 512 * 2, stream);  // h buf0, both dirs
    (void)hipMemsetAsync(cEnc, 0, 2ull * 1024 * 512 * 4, stream);

    kdetect<<<1, 128, 0, stream>>>((const unsigned int*)E_raw, mode);

    kcvt_bf16<<<64, 256, 0, stream>>>(E_raw,  Ebf,  128 * 128, mode);
    kcvt_bf16<<<128, 256, 0, stream>>>(fe_raw, febf, 32 * 1024, mode);
    kcvt_f32<<<8, 256, 0, stream>>>(bF_raw, bFf, 2048, mode);
    kcvt_f32<<<8, 256, 0, stream>>>(bB_raw, bBf, 2048, mode);
    kcvt_f32<<<1, 256, 0, stream>>>(bcomp_raw, bcf, 64, mode);
    kcvt_f32<<<16, 256, 0, stream>>>(vb_raw, vbf, 4096, mode);

    ktranspose_cvt<<<dim3(32, 8),  256, 0, stream>>>(WhF_raw,   WhT,              512, 2048, mode);
    ktranspose_cvt<<<dim3(32, 8),  256, 0, stream>>>(WhB_raw,   WhT + 2048 * 512, 512, 2048, mode);
    ktranspose_cvt<<<dim3(32, 4),  256, 0, stream>>>(WiF_raw,   WiT,              256, 2048, mode);
    ktranspose_cvt<<<dim3(32, 4),  256, 0, stream>>>(WiB_raw,   WiT + 2048 * 256, 256, 2048, mode);
    ktranspose_cvt<<<dim3(64, 16), 256, 0, stream>>>(vWh_raw,   vWhT,            1024, 4096, mode);
    ktranspose_cvt<<<dim3(64, 16), 256, 0, stream>>>(vWi_raw,   vWiT,            1024, 4096, mode);
    ktranspose_cvt<<<dim3(16, 16), 256, 0, stream>>>(Wattn_raw, WattnT,          1024, 1024, mode);
    ktranspose_cvt<<<dim3(1, 32),  256, 0, stream>>>(Wcomp_raw, WcT,             2048, 64,   mode);

    kprep_gtab<<<256, 256, 0, stream>>>(Ebf, WiT, bFf, bBf, Gtab);
    kprep_vx<<<32, 256, 0, stream>>>(febf, vWiT, vbf, VX);

    const size_t HB = 2ull * 1024 * 512;
    for (int t = 0; t < 64; t++) {
        kenc_step<<<512, 256, 0, stream>>>(t, WhT, Gtab, exs, cls,
                                           hEnc + (size_t)(t & 1) * HB,
                                           hEnc + (size_t)((t + 1) & 1) * HB,
                                           cEnc, ctx8);
    }
    kinit_dec<<<1024, 256, 0, stream>>>(hEnc, cEnc, hAll, cDec);

    const size_t HD = 256ull * 1024;
    for (int t = 0; t < 32; t++) {
        kdec_gemm<<<256, 256, 0, stream>>>(t, vWhT, WattnT, VX,
                                           hAll + (size_t)t * HD,
                                           hAll + (size_t)(t + 1) * HD,
                                           cDec, qall + (size_t)t * HD);
    }
    kattn_all<<<dim3(256, 32), 512, 0, stream>>>(qall, ctx8, hAll, WcT, bcf,
                                                 actions, nllT);
    kfinal<<<1, 256, 0, stream>>>(nllT, d_out, mode);
}

// Round 9
// 1907.664 us; speedup vs baseline: 3.3736x; 1.2314x over previous
//
#include <hip/hip_runtime.h>
#include <hip/hip_bf16.h>

typedef __bf16 bf16x8 __attribute__((ext_vector_type(8)));
typedef float  f32x4  __attribute__((ext_vector_type(4)));
typedef float  f32x2  __attribute__((ext_vector_type(2)));
typedef unsigned int u32x4 __attribute__((ext_vector_type(4)));
typedef unsigned short ushort_t;
static_assert(sizeof(bf16x8) == 16, "bf16x8 must be 16B");

#define DEV __device__ __forceinline__

DEV f32x4 mfma16(bf16x8 a, bf16x8 b, f32x4 c) {
    return __builtin_amdgcn_mfma_f32_16x16x32_bf16(a, b, c, 0, 0, 0);
}
DEV f32x4 mfma8(long a, long b, f32x4 c) {
    return __builtin_amdgcn_mfma_f32_16x16x32_fp8_fp8(a, b, c, 0, 0, 0);
}
DEV float wsum(float v) {
#pragma unroll
    for (int o = 32; o > 0; o >>= 1) v += __shfl_xor(v, o, 64);
    return v;
}
DEV float sigm(float x)   { return 1.0f / (1.0f + __expf(-x)); }
DEV float tanh_f(float x) { return 2.0f / (1.0f + __expf(-2.0f * x)) - 1.0f; }

// async global->LDS, 16B per lane; lds dest must be wave-uniform base (+lane*16)
DEV void glds16(const __hip_bfloat16* g, __hip_bfloat16* l) {
    __builtin_amdgcn_global_load_lds(
        (const __attribute__((address_space(1))) unsigned int*)g,
        (__attribute__((address_space(3))) unsigned int*)l, 16, 0, 0);
}

DEV unsigned char f32_to_fp8(float v) {
    int p = __builtin_amdgcn_cvt_pk_fp8_f32(v, v, 0, false);
    return (unsigned char)(p & 0xFF);
}

// ---------------- dtype detection: 1 = inputs are bf16, 0 = inputs are fp32 --
__global__ __launch_bounds__(128) void kdetect(const unsigned int* __restrict__ raw,
                                               int* __restrict__ mode) {
    __shared__ int cnt;
    if (threadIdx.x == 0) cnt = 0;
    __syncthreads();
    unsigned int w = raw[threadIdx.x];
    unsigned short lo = (unsigned short)(w & 0xFFFFu);
    unsigned int f32bits = ((unsigned int)lo) << 16;
    float v;
    __builtin_memcpy(&v, &f32bits, 4);
    float a = fabsf(v);
    if (a >= 1e-4f && a <= 1.0f) atomicAdd(&cnt, 1);
    __syncthreads();
    if (threadIdx.x == 0) *mode = (cnt >= 64) ? 1 : 0;
}

__global__ __launch_bounds__(256) void kcvt_bf16(const void* __restrict__ src,
                                                 __hip_bfloat16* __restrict__ dst,
                                                 int n, const int* __restrict__ mode) {
    int i = blockIdx.x * 256 + threadIdx.x;
    if (i >= n) return;
    if (*mode) dst[i] = ((const __hip_bfloat16*)src)[i];
    else       dst[i] = __float2bfloat16(((const float*)src)[i]);
}

__global__ __launch_bounds__(256) void kcvt_f32(const void* __restrict__ src,
                                                float* __restrict__ dst,
                                                int n, const int* __restrict__ mode) {
    int i = blockIdx.x * 256 + threadIdx.x;
    if (i >= n) return;
    if (*mode) dst[i] = __bfloat162float(((const __hip_bfloat16*)src)[i]);
    else       dst[i] = ((const float*)src)[i];
}

// --------- tiled transpose + convert: out_bf16[c][r] = (bf16)in[r][c] --------
__global__ __launch_bounds__(256) void ktranspose_cvt(const void* __restrict__ src,
                                                      __hip_bfloat16* __restrict__ out,
                                                      int R, int C,
                                                      const int* __restrict__ mode) {
    __shared__ float tile[64][65];
    int c0 = blockIdx.x * 64, r0 = blockIdx.y * 64;
    int tx = threadIdx.x & 63, ty = threadIdx.x >> 6;
    int m = *mode;
#pragma unroll
    for (int i = ty; i < 64; i += 4) {
        size_t ix = (size_t)(r0 + i) * C + (c0 + tx);
        tile[i][tx] = m ? __bfloat162float(((const __hip_bfloat16*)src)[ix])
                        : ((const float*)src)[ix];
    }
    __syncthreads();
#pragma unroll
    for (int i = ty; i < 64; i += 4)
        out[(size_t)(c0 + i) * R + (r0 + tx)] = __float2bfloat16(tile[tx][i]);
}

// ------ prep: G tables, gate-interleaved: G[dh][v][u<512][g<4] = E@Wi (+b) ---
__global__ __launch_bounds__(256) void kprep_gtab(
    const __hip_bfloat16* __restrict__ E,    // [128][128]
    const __hip_bfloat16* __restrict__ WiT,  // [2][2048][256]
    const float* __restrict__ bF,
    const float* __restrict__ bB,
    float* __restrict__ G)                   // [4][128][512][4]
{
    int dh = blockIdx.x >> 6;
    int dir = dh >> 1, half = dh & 1;
    int m0 = ((blockIdx.x >> 5) & 1) * 64;
    int n0 = (blockIdx.x & 31) * 64;
    int lane = threadIdx.x & 63, wid = threadIdx.x >> 6;
    int wrow = wid >> 1, wcol = wid & 1;
    int r16 = lane & 15, quad = lane >> 4;

    f32x4 acc[2][2] = {};
    const __hip_bfloat16* Ap = E + (size_t)(m0 + wrow * 32 + r16) * 128 + quad * 8;
    const __hip_bfloat16* Bp = WiT + (size_t)dir * 2048 * 256
                             + (size_t)(n0 + wcol * 32 + r16) * 256 + half * 128 + quad * 8;
#pragma unroll
    for (int kb = 0; kb < 128; kb += 32) {
        bf16x8 a0 = *(const bf16x8*)(Ap + kb);
        bf16x8 a1 = *(const bf16x8*)(Ap + 16 * 128 + kb);
        bf16x8 b0 = *(const bf16x8*)(Bp + kb);
        bf16x8 b1 = *(const bf16x8*)(Bp + 16 * 256 + kb);
        acc[0][0] = mfma16(a0, b0, acc[0][0]);
        acc[0][1] = mfma16(a0, b1, acc[0][1]);
        acc[1][0] = mfma16(a1, b0, acc[1][0]);
        acc[1][1] = mfma16(a1, b1, acc[1][1]);
    }
    const float* bias = dir ? bB : bF;
    float* Gt = G + (size_t)dh * 128 * 2048;
#pragma unroll
    for (int rt = 0; rt < 2; rt++)
#pragma unroll
        for (int ct = 0; ct < 2; ct++)
#pragma unroll
            for (int r = 0; r < 4; r++) {
                int mm = m0 + wrow * 32 + rt * 16 + quad * 4 + r;
                int j = n0 + wcol * 32 + ct * 16 + r16;
                float v = acc[rt][ct][r];
                if (half == 0) v += bias[j];
                int g = j >> 9, u = j & 511;
                Gt[((size_t)mm * 512 + u) * 4 + g] = v;
            }
}

// ---------------- prep: VX[t][j] = field_emb @ v_Wi + v_b --------------------
__global__ __launch_bounds__(256) void kprep_vx(
    const __hip_bfloat16* __restrict__ fe,    // [32][1024]
    const __hip_bfloat16* __restrict__ vWiT,  // [4096][1024]
    const float* __restrict__ vb,             // [4096]
    float* __restrict__ VX)                   // [32][4096]
{
    int n0 = blockIdx.x * 128;
    int lane = threadIdx.x & 63, wid = threadIdx.x >> 6;
    int r16 = lane & 15, quad = lane >> 4;
    f32x4 acc[2][2] = {};
    const __hip_bfloat16* Ap = fe + (size_t)r16 * 1024 + quad * 8;
    const __hip_bfloat16* Bp = vWiT + (size_t)(n0 + wid * 32 + r16) * 1024 + quad * 8;
    for (int kb = 0; kb < 1024; kb += 32) {
        bf16x8 a0 = *(const bf16x8*)(Ap + kb);
        bf16x8 a1 = *(const bf16x8*)(Ap + 16 * 1024 + kb);
        bf16x8 b0 = *(const bf16x8*)(Bp + kb);
        bf16x8 b1 = *(const bf16x8*)(Bp + 16 * 1024 + kb);
        acc[0][0] = mfma16(a0, b0, acc[0][0]);
        acc[0][1] = mfma16(a0, b1, acc[0][1]);
        acc[1][0] = mfma16(a1, b0, acc[1][0]);
        acc[1][1] = mfma16(a1, b1, acc[1][1]);
    }
#pragma unroll
    for (int rt = 0; rt < 2; rt++)
#pragma unroll
        for (int ct = 0; ct < 2; ct++)
#pragma unroll
            for (int r = 0; r < 4; r++) {
                int m = rt * 16 + quad * 4 + r;
                int j = n0 + wid * 32 + ct * 16 + r16;
                VX[(size_t)m * 4096 + j] = acc[rt][ct][r] + vb[j];
            }
}

// ======== encoder LSTM step: 512 blocks (dir x 32 mt x 8 us), 32m x 64u ======
__global__ __launch_bounds__(256, 2) void kenc_step(
    int t,
    const __hip_bfloat16* __restrict__ WhT,   // [2][2048][512]
    const float* __restrict__ Gtab,           // [4][128][512][4]
    const int* __restrict__ exs,
    const int* __restrict__ cls,
    const __hip_bfloat16* __restrict__ h_in,  // [2][1024][512]
    __hip_bfloat16* __restrict__ h_out,
    float* __restrict__ c_st,                 // [2][1024][512]
    unsigned char* __restrict__ ctx8)         // [64][256][4][1024] fp8 (x16)
{
    __shared__ __align__(16) __hip_bfloat16 sA[2][32 * 64];
    __shared__ __align__(16) __hip_bfloat16 sB[2][256 * 64];

    int bid = blockIdx.x;
    int dir = bid >> 8;
    int mt  = (bid >> 3) & 31;
    int us  = bid & 7;
    int l = dir ? (63 - t) : t;
    int m0 = mt * 32, u0 = us * 64;

    int lane = threadIdx.x & 63, w = threadIdx.x >> 6;
    int r16 = lane & 15, quad = lane >> 4;
    int srow = lane >> 3, scol = (lane & 7) * 8;   // 8 rows per glds16 call

    const __hip_bfloat16* Ab = h_in + (size_t)dir * 1024 * 512;
    const __hip_bfloat16* Bb = WhT + (size_t)dir * 2048 * 512;

    f32x4 acc[4][2] = {};  // [gate][mi]

    auto stage = [&](int buf, int it) {
        int kb = it * 64;
        glds16(Ab + (size_t)(m0 + w * 8 + srow) * 512 + kb + scol,
               &sA[buf][(w * 8) * 64]);
#pragma unroll
        for (int c = 0; c < 8; c++) {
            int rl = w * 64 + c * 8;
            int rr = rl + srow;
            int g = rr >> 6, j = rr & 63;
            glds16(Bb + (size_t)(g * 512 + u0 + j) * 512 + kb + scol,
                   &sB[buf][rl * 64]);
        }
    };

    stage(0, 0);
    __syncthreads();
    int buf = 0;
    const int NIT = 8;  // 512/64
    for (int it = 0; it < NIT; it++) {
        if (it + 1 < NIT) stage(buf ^ 1, it + 1);
#pragma unroll
        for (int k32 = 0; k32 < 64; k32 += 32) {
            bf16x8 a[2], bf[4];
#pragma unroll
            for (int mi = 0; mi < 2; mi++)
                a[mi] = *(const bf16x8*)&sA[buf][(mi * 16 + r16) * 64 + k32 + quad * 8];
#pragma unroll
            for (int g = 0; g < 4; g++)
                bf[g] = *(const bf16x8*)&sB[buf][(g * 64 + w * 16 + r16) * 64 + k32 + quad * 8];
#pragma unroll
            for (int g = 0; g < 4; g++)
#pragma unroll
                for (int mi = 0; mi < 2; mi++)
                    acc[g][mi] = mfma16(a[mi], bf[g], acc[g][mi]);
        }
        __syncthreads();
        buf ^= 1;
    }

    // epilogue: thread owns u = u0 + w*16 + r16, 8 m's
    int u = u0 + w * 16 + r16;
    size_t cbase = (size_t)dir * 1024 * 512;
    const float* GeT = Gtab + (size_t)(dir * 2) * 128 * 2048;
    const float* GcT = GeT + 128 * 2048;
#pragma unroll
    for (int mi = 0; mi < 2; mi++)
#pragma unroll
        for (int r = 0; r < 4; r++) {
            int m = m0 + mi * 16 + quad * 4 + r;
            int vE = exs[l * 1024 + m], vC = cls[l * 1024 + m];
            f32x4 ge = *(const f32x4*)&GeT[((size_t)vE * 512 + u) * 4];
            f32x4 gc = *(const f32x4*)&GcT[((size_t)vC * 512 + u) * 4];
            float gi = acc[0][mi][r] + ge[0] + gc[0];
            float gf = acc[1][mi][r] + ge[1] + gc[1];
            float gg = acc[2][mi][r] + ge[2] + gc[2];
            float go = acc[3][mi][r] + ge[3] + gc[3];
            size_t cix = cbase + (size_t)m * 512 + u;
            float cn = sigm(gf) * c_st[cix] + sigm(gi) * tanh_f(gg);
            c_st[cix] = cn;
            float hn = sigm(go) * tanh_f(cn);
            h_out[cix] = __float2bfloat16(hn);
            ctx8[(((size_t)l * 256 + (m >> 2)) * 4 + (m & 3)) * 1024 + dir * 512 + u]
                = f32_to_fp8(hn * 16.0f);
        }
}

// ---- fp8 ctx transpose: ctxT8[b4n][e][l] = ctx8[l][b4n][e] ------------------
__global__ __launch_bounds__(256) void ktrans8(const unsigned char* __restrict__ ctx8,
                                               unsigned char* __restrict__ ctxT8) {
    __shared__ unsigned int tile[64][17];   // 64 l-rows x 64 e-bytes (16 u32 + pad)
    int b4n = blockIdx.x;                   // 0..1023
    int e0 = blockIdx.y * 64;               // e-tile
    int tid = threadIdx.x;
#pragma unroll
    for (int pass = 0; pass < 4; pass++) {
        int idx = pass * 256 + tid;
        int l = idx >> 4, c = idx & 15;
        tile[l][c] = *(const unsigned int*)(ctx8 + (size_t)l * (1024 * 1024)
                                            + (size_t)b4n * 1024 + e0 + c * 4);
    }
    __syncthreads();
    const unsigned char* tb = (const unsigned char*)tile;
#pragma unroll
    for (int pass = 0; pass < 4; pass++) {
        int idx = pass * 256 + tid;
        int e = idx >> 4, c = idx & 15;
        unsigned int v = 0;
#pragma unroll
        for (int j = 0; j < 4; j++) {
            unsigned int byte = tb[(size_t)(c * 4 + j) * 68 + e];
            v |= byte << (8 * j);
        }
        *(unsigned int*)(ctxT8 + ((size_t)b4n * 1024 + e0 + e) * 64 + c * 4) = v;
    }
}

// ======== decoder fused GEMM: cell (0..127: 32m x 64u) + q (128..255) ========
__global__ __launch_bounds__(256, 2) void kdec_gemm(
    int t,
    const __hip_bfloat16* __restrict__ vWhT,   // [4096][1024]
    const __hip_bfloat16* __restrict__ WattnT, // [1024][1024]
    const float* __restrict__ VX,              // [32][4096]
    const __hip_bfloat16* __restrict__ h_in,   // [256][1024]  (h_t = hAll[t])
    __hip_bfloat16* __restrict__ h_out,        // [256][1024]  (hAll[t+1])
    float* __restrict__ c_st,                  // [256][1024]
    float* __restrict__ qout)                  // [256][1024]  (qall[t])
{
    __shared__ __align__(16) __hip_bfloat16 sA[2][32 * 64];
    __shared__ __align__(16) __hip_bfloat16 sB[2][256 * 64];

    int bid = blockIdx.x;
    int lane = threadIdx.x & 63, w = threadIdx.x >> 6;
    int r16 = lane & 15, quad = lane >> 4;
    int srow = lane >> 3, scol = (lane & 7) * 8;
    const int NIT = 16;  // 1024/64

    if (bid < 128) {
        int m0 = (bid >> 4) * 32, u0 = (bid & 15) * 64;
        f32x4 acc[4][2] = {};
        auto stage = [&](int buf, int it) {
            int kb = it * 64;
            glds16(h_in + (size_t)(m0 + w * 8 + srow) * 1024 + kb + scol,
                   &sA[buf][(w * 8) * 64]);
#pragma unroll
            for (int c = 0; c < 8; c++) {
                int rl = w * 64 + c * 8;
                int rr = rl + srow;
                int g = rr >> 6, j = rr & 63;
                glds16(vWhT + (size_t)(g * 1024 + u0 + j) * 1024 + kb + scol,
                       &sB[buf][rl * 64]);
            }
        };
        stage(0, 0);
        __syncthreads();
        int buf = 0;
        for (int it = 0; it < NIT; it++) {
            if (it + 1 < NIT) stage(buf ^ 1, it + 1);
#pragma unroll
            for (int k32 = 0; k32 < 64; k32 += 32) {
                bf16x8 a[2], bf[4];
#pragma unroll
                for (int mi = 0; mi < 2; mi++)
                    a[mi] = *(const bf16x8*)&sA[buf][(mi * 16 + r16) * 64 + k32 + quad * 8];
#pragma unroll
                for (int g = 0; g < 4; g++)
                    bf[g] = *(const bf16x8*)&sB[buf][(g * 64 + w * 16 + r16) * 64 + k32 + quad * 8];
#pragma unroll
                for (int g = 0; g < 4; g++)
#pragma unroll
                    for (int mi = 0; mi < 2; mi++)
                        acc[g][mi] = mfma16(a[mi], bf[g], acc[g][mi]);
            }
            __syncthreads();
            buf ^= 1;
        }
        int u = u0 + w * 16 + r16;
        const float* vx = VX + (size_t)t * 4096;
        float v0 = vx[u], v1 = vx[1024 + u], v2 = vx[2048 + u], v3 = vx[3072 + u];
#pragma unroll
        for (int mi = 0; mi < 2; mi++)
#pragma unroll
            for (int r = 0; r < 4; r++) {
                int m = m0 + mi * 16 + quad * 4 + r;
                float gi = acc[0][mi][r] + v0;
                float gf = acc[1][mi][r] + v1;
                float gg = acc[2][mi][r] + v2;
                float go = acc[3][mi][r] + v3;
                size_t cix = (size_t)m * 1024 + u;
                float cn = sigm(gf) * c_st[cix] + sigm(gi) * tanh_f(gg);
                c_st[cix] = cn;
                h_out[cix] = __float2bfloat16(sigm(go) * tanh_f(cn));
            }
    } else {
        int b2 = bid - 128;
        int m0 = (b2 >> 4) * 32, n0 = (b2 & 15) * 64;
        f32x4 acc[2] = {};
        auto stage = [&](int buf, int it) {
            int kb = it * 64;
            glds16(h_in + (size_t)(m0 + w * 8 + srow) * 1024 + kb + scol,
                   &sA[buf][(w * 8) * 64]);
#pragma unroll
            for (int c = 0; c < 2; c++) {
                int rl = w * 16 + c * 8;
                glds16(WattnT + (size_t)(n0 + rl + srow) * 1024 + kb + scol,
                       &sB[buf][rl * 64]);
            }
        };
        stage(0, 0);
        __syncthreads();
        int buf = 0;
        for (int it = 0; it < NIT; it++) {
            if (it + 1 < NIT) stage(buf ^ 1, it + 1);
#pragma unroll
            for (int k32 = 0; k32 < 64; k32 += 32) {
                bf16x8 a[2];
#pragma unroll
                for (int mi = 0; mi < 2; mi++)
                    a[mi] = *(const bf16x8*)&sA[buf][(mi * 16 + r16) * 64 + k32 + quad * 8];
                bf16x8 bf = *(const bf16x8*)&sB[buf][(w * 16 + r16) * 64 + k32 + quad * 8];
#pragma unroll
                for (int mi = 0; mi < 2; mi++)
                    acc[mi] = mfma16(a[mi], bf, acc[mi]);
            }
            __syncthreads();
            buf ^= 1;
        }
        int n = n0 + w * 16 + r16;
#pragma unroll
        for (int mi = 0; mi < 2; mi++)
#pragma unroll
            for (int r = 0; r < 4; r++) {
                int m = m0 + mi * 16 + quad * 4 + r;
                qout[(size_t)m * 1024 + n] = acc[mi][r];
            }
    }
}

// ======== MFMA attention: block = b, all 32 t batched ========================
// GEMM1 (fp8): S[t][l] = q8[t]·ctx8[l]   M=32 N=64 K=1024  (per io-example n)
// softmax over l (max-free) -> P fp8 (x16/S)
// GEMM2 (fp8): O[t][e] = P[t]·ctxT8[e]   M=32 N=1024 K=64, max-pool over n
// GEMM3 (bf16): logits[t][p] = concat(h,pool)[t]·Wc[p]  M=32 N=64 K=2048
__global__ __launch_bounds__(512, 2) void kattn_mfma(
    const float* __restrict__ qall,           // [32][256][1024]
    const unsigned char* __restrict__ ctx8,   // [64][1024][1024] fp8 (x16)
    const unsigned char* __restrict__ ctxT8,  // [1024][1024][64] fp8 (x16)
    const __hip_bfloat16* __restrict__ hAll,  // [33][256][1024]
    const __hip_bfloat16* __restrict__ WcT,   // [64][2048]
    const float* __restrict__ bcomp,          // [64]
    const int* __restrict__ actions,          // [256][32]
    float* __restrict__ nllT)                 // [32][256]
{
    __shared__ __align__(16) unsigned char sQ8[32 * 1032];   // q fp8 (/4), row stride 1032
    __shared__ float sS[4][32][65];                          // scores
    __shared__ __align__(16) unsigned char sP[4 * 32 * 72];  // P fp8 (x16/S), stride 72
    __shared__ __align__(16) ushort_t sPool[32 * 1032];      // pooled ctx bf16, stride 1032
    __shared__ float slg[32 * 68];                           // logits

    int b = blockIdx.x;
    int tid = threadIdx.x;
    int lane = tid & 63, w = tid >> 6;
    int r16 = lane & 15, quad = lane >> 4;
    const size_t LSTR = 1024 * 1024;

    // ---- phase Q: qall fp32 -> fp8 (x 1/4) into LDS
    for (int i = 0; i < 64; i++) {
        int idx = i * 512 + tid;           // coalesced over tid
        int t = idx >> 10, e = idx & 1023;
        float v = qall[((size_t)t * 256 + b) * 1024 + e] * 0.25f;
        sQ8[t * 1032 + e] = f32_to_fp8(v);
    }
    __syncthreads();

    // ---- GEMM1: wave w -> (n = w>>1, l-half lh = w&1)
    {
        int n = w >> 1, lh = w & 1;
        int l0 = lh * 32;
        f32x4 c[2][2] = {};
        const unsigned char* cbase = ctx8 + (size_t)(b * 4 + n) * 1024;
        for (int k0 = 0; k0 < 1024; k0 += 32) {
            long a[2], bv[2];
#pragma unroll
            for (int mt = 0; mt < 2; mt++)
                __builtin_memcpy(&a[mt], &sQ8[(mt * 16 + r16) * 1032 + k0 + quad * 8], 8);
#pragma unroll
            for (int lt = 0; lt < 2; lt++)
                bv[lt] = *(const long*)(cbase + (size_t)(l0 + lt * 16 + r16) * LSTR
                                        + k0 + quad * 8);
#pragma unroll
            for (int mt = 0; mt < 2; mt++)
#pragma unroll
                for (int lt = 0; lt < 2; lt++)
                    c[mt][lt] = mfma8(a[mt], bv[lt], c[mt][lt]);
        }
#pragma unroll
        for (int mt = 0; mt < 2; mt++)
#pragma unroll
            for (int lt = 0; lt < 2; lt++)
#pragma unroll
                for (int r = 0; r < 4; r++)
                    sS[n][mt * 16 + quad * 4 + r][l0 + lt * 16 + r16] = c[mt][lt][r];
    }
    __syncthreads();

    // ---- softmax over l, P = fp8(16 * p / S). s = D/4 (q was /4, ctx x16).
    if (tid < 128) {
        int n = tid >> 5, t = tid & 31;
        const float* row = &sS[n][t][0];
        float sum = 0.f;
        for (int l = 0; l < 64; l++)
            sum += __expf(fminf(row[l] * 0.25f, 60.f));
        float inv = 16.0f / sum;
        unsigned char* pr = &sP[(n * 32 + t) * 72];
        for (int l = 0; l < 64; l++)
            pr[l] = f32_to_fp8(__expf(fminf(row[l] * 0.25f, 60.f)) * inv);
    }
    __syncthreads();

    // ---- GEMM2: wave w -> e-range [w*128, w*128+128), loop n, pool in regs
    {
        int e0 = w * 128;
        f32x4 pool[2][8];
#pragma unroll
        for (int mt = 0; mt < 2; mt++)
#pragma unroll
            for (int et = 0; et < 8; et++)
#pragma unroll
                for (int r = 0; r < 4; r++) pool[mt][et][r] = -3.4e38f;

        for (int n = 0; n < 4; n++) {
            f32x4 c[2][8] = {};
            const unsigned char* tbase = ctxT8 + (size_t)(b * 4 + n) * 1024 * 64;
#pragma unroll
            for (int k0 = 0; k0 < 64; k0 += 32) {
                long a[2];
#pragma unroll
                for (int mt = 0; mt < 2; mt++)
                    __builtin_memcpy(&a[mt], &sP[(n * 32 + mt * 16 + r16) * 72 + k0 + quad * 8], 8);
#pragma unroll
                for (int et = 0; et < 8; et++) {
                    long bv = *(const long*)(tbase + (size_t)(e0 + et * 16 + r16) * 64
                                             + k0 + quad * 8);
#pragma unroll
                    for (int mt = 0; mt < 2; mt++)
                        c[mt][et] = mfma8(a[mt], bv, c[mt][et]);
                }
            }
#pragma unroll
            for (int mt = 0; mt < 2; mt++)
#pragma unroll
                for (int et = 0; et < 8; et++)
#pragma unroll
                    for (int r = 0; r < 4; r++)
                        pool[mt][et][r] = fmaxf(pool[mt][et][r], c[mt][et][r] * (1.0f / 256.0f));
        }
#pragma unroll
        for (int mt = 0; mt < 2; mt++)
#pragma unroll
            for (int et = 0; et < 8; et++)
#pragma unroll
                for (int r = 0; r < 4; r++) {
                    int t = mt * 16 + quad * 4 + r;
                    int e = e0 + et * 16 + r16;
                    __hip_bfloat16 hb = __float2bfloat16(pool[mt][et][r]);
                    sPool[t * 1032 + e] = *(ushort_t*)&hb;
                }
    }
    __syncthreads();

    // ---- GEMM3 logits: wave w -> (mt = w&1, pt = w>>1)
    {
        int mt = w & 1, pt = w >> 1;
        f32x4 c = {};
        const __hip_bfloat16* hrow = hAll + ((size_t)(mt * 16 + r16) * 256 + b) * 1024;
        const __hip_bfloat16* wrow = WcT + (size_t)(pt * 16 + r16) * 2048;
        for (int k0 = 0; k0 < 2048; k0 += 32) {
            bf16x8 a;
            if (k0 < 1024)
                a = *(const bf16x8*)(hrow + k0 + quad * 8);
            else
                a = *(const bf16x8*)&sPool[(mt * 16 + r16) * 1032 + (k0 - 1024) + quad * 8];
            bf16x8 bv = *(const bf16x8*)(wrow + k0 + quad * 8);
            c = mfma16(a, bv, c);
        }
#pragma unroll
        for (int r = 0; r < 4; r++) {
            int t = mt * 16 + quad * 4 + r;
            int p = pt * 16 + r16;
            slg[t * 68 + p] = c[r] + bcomp[p];
        }
    }
    __syncthreads();

    // ---- NLL per t
    if (tid < 32) {
        int t = tid;
        const float* row = &slg[t * 68];
        float m = -3.4e38f;
        for (int p = 0; p < 64; p++) m = fmaxf(m, row[p]);
        float se = 0.f;
        for (int p = 0; p < 64; p++) se += __expf(row[p] - m);
        int a = actions[b * 32 + t];
        nllT[t * 256 + b] = m + __logf(se) - row[a];
    }
}

// ---------------- decoder init: max-pool final states over io examples -------
__global__ __launch_bounds__(256) void kinit_dec(
    const __hip_bfloat16* __restrict__ hf,  // final h (buf0): [2][1024][512]
    const float* __restrict__ cf,
    __hip_bfloat16* __restrict__ h0,        // [256][1024] (hAll[0])
    float* __restrict__ c0)
{
    int idx = blockIdx.x * 256 + threadIdx.x;
    int b = idx >> 10, e = idx & 1023;
    int dir = e >> 9, u = e & 511;
    const __hip_bfloat16* hs = hf + (size_t)dir * 1024 * 512;
    const float* cs = cf + (size_t)dir * 1024 * 512;
    float hv = -3.4e38f, cv = -3.4e38f;
#pragma unroll
    for (int n = 0; n < 4; n++) {
        size_t ix = (size_t)(b * 4 + n) * 512 + u;
        hv = fmaxf(hv, __bfloat162float(hs[ix]));
        cv = fmaxf(cv, cs[ix]);
    }
    h0[idx] = __float2bfloat16(hv);
    c0[idx] = cv;
}

__global__ void kfinal(const float* __restrict__ nllT, void* __restrict__ out,
                       const int* __restrict__ mode) {
    int i = threadIdx.x;
    float s = 0.f;
#pragma unroll
    for (int t = 0; t < 32; t++) s += nllT[t * 256 + i];
    if (*mode) ((__hip_bfloat16*)out)[i] = __float2bfloat16(s);
    else       ((float*)out)[i] = s;
}

// -----------------------------------------------------------------------------
extern "C" void kernel_launch(void* const* d_in, const int* in_sizes, int n_in,
                              void* d_out, int out_size, void* d_ws, size_t ws_size,
                              hipStream_t stream) {
    const int* exs = (const int*)d_in[0];
    const int* cls = (const int*)d_in[1];
    const void* E_raw     = d_in[2];
    const void* WiF_raw   = d_in[3];
    const void* WhF_raw   = d_in[4];
    const void* bF_raw    = d_in[5];
    const void* WiB_raw   = d_in[6];
    const void* WhB_raw   = d_in[7];
    const void* bB_raw    = d_in[8];
    const void* Wattn_raw = d_in[9];
    const void* Wcomp_raw = d_in[10];
    const void* bcomp_raw = d_in[11];
    const void* vWi_raw   = d_in[12];
    const void* vWh_raw   = d_in[13];
    const void* vb_raw    = d_in[14];
    const void* fe_raw    = d_in[15];
    const int* actions = (const int*)d_in[16];
    (void)in_sizes; (void)n_in; (void)out_size; (void)ws_size;

    char* w = (char*)d_ws;
    size_t off = 0;
    auto take = [&](size_t bytes) -> char* {
        char* p = w + off;
        off = (off + bytes + 255) & ~(size_t)255;
        return p;
    };
    __hip_bfloat16* WhT    = (__hip_bfloat16*)take(2ull * 2048 * 512 * 2);
    __hip_bfloat16* WiT    = (__hip_bfloat16*)take(2ull * 2048 * 256 * 2);
    __hip_bfloat16* vWhT   = (__hip_bfloat16*)take(4096ull * 1024 * 2);
    __hip_bfloat16* vWiT   = (__hip_bfloat16*)take(4096ull * 1024 * 2);
    __hip_bfloat16* WattnT = (__hip_bfloat16*)take(1024ull * 1024 * 2);
    __hip_bfloat16* WcT    = (__hip_bfloat16*)take(64ull * 2048 * 2);
    __hip_bfloat16* Ebf    = (__hip_bfloat16*)take(128ull * 128 * 2);
    __hip_bfloat16* febf   = (__hip_bfloat16*)take(32ull * 1024 * 2);
    float* bFf   = (float*)take(2048 * 4);
    float* bBf   = (float*)take(2048 * 4);
    float* bcf   = (float*)take(64 * 4);
    float* vbf   = (float*)take(4096 * 4);
    float* Gtab  = (float*)take(4ull * 128 * 2048 * 4);
    float* VX    = (float*)take(32ull * 4096 * 4);
    __hip_bfloat16* hEnc = (__hip_bfloat16*)take(2ull * 2 * 1024 * 512 * 2); // [buf][dir][1024][512]
    float* cEnc = (float*)take(2ull * 1024 * 512 * 4);
    __hip_bfloat16* hAll = (__hip_bfloat16*)take(33ull * 256 * 1024 * 2);    // h_0..h_32
    float* cDec = (float*)take(256ull * 1024 * 4);
    float* qall = (float*)take(32ull * 256 * 1024 * 4);
    float* nllT = (float*)take(32ull * 256 * 4);
    int*   mode = (int*)take(256);
    unsigned char* ctx8  = (unsigned char*)take(64ull * 1024 * 1024);  // fp8 [l][b4n][e]
    unsigned char* ctxT8 = (unsigned char*)take(64ull * 1024 * 1024);  // fp8 [b4n][e][l]

    (void)hipMemsetAsync(hEnc, 0, 2ull * 1024 * 512 * 2, stream);  // h buf0, both dirs
    (void)hipMemsetAsync(cEnc, 0, 2ull * 1024 * 512 * 4, stream);

    kdetect<<<1, 128, 0, stream>>>((const unsigned int*)E_raw, mode);

    kcvt_bf16<<<64, 256, 0, stream>>>(E_raw,  Ebf,  128 * 128, mode);
    kcvt_bf16<<<128, 256, 0, stream>>>(fe_raw, febf, 32 * 1024, mode);
    kcvt_f32<<<8, 256, 0, stream>>>(bF_raw, bFf, 2048, mode);
    kcvt_f32<<<8, 256, 0, stream>>>(bB_raw, bBf, 2048, mode);
    kcvt_f32<<<1, 256, 0, stream>>>(bcomp_raw, bcf, 64, mode);
    kcvt_f32<<<16, 256, 0, stream>>>(vb_raw, vbf, 4096, mode);

    ktranspose_cvt<<<dim3(32, 8),  256, 0, stream>>>(WhF_raw,   WhT,              512, 2048, mode);
    ktranspose_cvt<<<dim3(32, 8),  256, 0, stream>>>(WhB_raw,   WhT + 2048 * 512, 512, 2048, mode);
    ktranspose_cvt<<<dim3(32, 4),  256, 0, stream>>>(WiF_raw,   WiT,              256, 2048, mode);
    ktranspose_cvt<<<dim3(32, 4),  256, 0, stream>>>(WiB_raw,   WiT + 2048 * 256, 256, 2048, mode);
    ktranspose_cvt<<<dim3(64, 16), 256, 0, stream>>>(vWh_raw,   vWhT,            1024, 4096, mode);
    ktranspose_cvt<<<dim3(64, 16), 256, 0, stream>>>(vWi_raw,   vWiT,            1024, 4096, mode);
    ktranspose_cvt<<<dim3(16, 16), 256, 0, stream>>>(Wattn_raw, WattnT,          1024, 1024, mode);
    ktranspose_cvt<<<dim3(1, 32),  256, 0, stream>>>(Wcomp_raw, WcT,             2048, 64,   mode);

    kprep_gtab<<<256, 256, 0, stream>>>(Ebf, WiT, bFf, bBf, Gtab);
    kprep_vx<<<32, 256, 0, stream>>>(febf, vWiT, vbf, VX);

    const size_t HB = 2ull * 1024 * 512;
    for (int t = 0; t < 64; t++) {
        kenc_step<<<512, 256, 0, stream>>>(t, WhT, Gtab, exs, cls,
                                           hEnc + (size_t)(t & 1) * HB,
                                           hEnc + (size_t)((t + 1) & 1) * HB,
                                           cEnc, ctx8);
    }
    ktrans8<<<dim3(1024, 16), 256, 0, stream>>>(ctx8, ctxT8);
    kinit_dec<<<1024, 256, 0, stream>>>(hEnc, cEnc, hAll, cDec);

    const size_t HD = 256ull * 1024;
    for (int t = 0; t < 32; t++) {
        kdec_gemm<<<256, 256, 0, stream>>>(t, vWhT, WattnT, VX,
                                           hAll + (size_t)t * HD,
                                           hAll + (size_t)(t + 1) * HD,
                                           cDec, qall + (size_t)t * HD);
    }
    kattn_mfma<<<256, 512, 0, stream>>>(qall, ctx8, ctxT8, hAll, WcT, bcf,
                                        actions, nllT);
    kfinal<<<1, 256, 0, stream>>>(nllT, d_out, mode);
}